// Round 3
// baseline (339.892 us; speedup 1.0000x reference)
//
#include <hip/hip_runtime.h>
#include <stdint.h>

#define DIM 768
#define NHEADS 12
#define HDIM 64
#define DHALF 32
#define NTOK 2048
#define LOG2E 1.44269504088896340736f

typedef unsigned short u16;
typedef unsigned int u32;
typedef __bf16 bf16x8 __attribute__((ext_vector_type(8)));
typedef short s16x8 __attribute__((ext_vector_type(8)));
typedef float f32x4 __attribute__((ext_vector_type(4)));

__device__ __forceinline__ f32x4 f4zero() { f32x4 z = {0.f, 0.f, 0.f, 0.f}; return z; }

// fp32 -> bf16 bits, round-to-nearest-even
__device__ __forceinline__ u16 f2bf(float f) {
    u32 u = __builtin_bit_cast(u32, f);
    u32 r = (u + 0x7FFFu + ((u >> 16) & 1u)) >> 16;
    return (u16)r;
}

// async global->LDS, 16B per lane. LDS dest = wave-uniform base + lane*16.
__device__ __forceinline__ void gld_lds16(void* lds, const void* g) {
    __builtin_amdgcn_global_load_lds((const __attribute__((address_space(1))) u32*)g,
                                     (__attribute__((address_space(3))) u32*)lds,
                                     16, 0, 0);
}

// ---------------------------------------------------------------------------
// fused fp32 -> bf16 cast of x, w_qkv, w_proj (one launch)
// ---------------------------------------------------------------------------
__global__ __launch_bounds__(256) void cast3_f32_to_bf16(const float* __restrict__ a, u16* __restrict__ oa, int na4,
                                                         const float* __restrict__ b, u16* __restrict__ ob, int nb4,
                                                         const float* __restrict__ c, u16* __restrict__ oc, int nc4) {
    int i = blockIdx.x * 256 + threadIdx.x;
    const float* src;
    u16* dst;
    int j = i;
    if (i < na4) { src = a; dst = oa; }
    else if (i < na4 + nb4) { src = b; dst = ob; j = i - na4; }
    else if (i < na4 + nb4 + nc4) { src = c; dst = oc; j = i - na4 - nb4; }
    else return;
    float4 v = ((const float4*)src)[j];
    u32 w0 = (u32)f2bf(v.x) | ((u32)f2bf(v.y) << 16);
    u32 w1 = (u32)f2bf(v.z) | ((u32)f2bf(v.w) << 16);
    ((uint2*)dst)[j] = make_uint2(w0, w1);
}

// ---------------------------------------------------------------------------
// bt-GEMM: C[M,N] = A[M,K] * B[N,K]^T (+bias), bf16 in, fp32 out.
// 128x128 tile, BK=32, 256 threads = 2x2 waves, each wave 64x64 (4x4 MFMA tiles).
// ---------------------------------------------------------------------------
__global__ __launch_bounds__(256) void gemm_bt(const u16* __restrict__ A, const u16* __restrict__ Bm,
                                               float* __restrict__ C, const float* __restrict__ bias,
                                               int M, int N, int K) {
    __shared__ __align__(16) u16 sA[128 * 32];
    __shared__ __align__(16) u16 sB[128 * 32];
    const int t = threadIdx.x;
    const int wave = t >> 6, lane = t & 63;
    const int quad = lane >> 4, l16 = lane & 15;
    const int bm = blockIdx.y * 128, bn = blockIdx.x * 128;
    const int wr = wave >> 1, wc = wave & 1;

    f32x4 acc[4][4];
#pragma unroll
    for (int i = 0; i < 4; i++)
#pragma unroll
        for (int j = 0; j < 4; j++) acc[i][j] = f4zero();

    for (int k0 = 0; k0 < K; k0 += 32) {
#pragma unroll
        for (int r = 0; r < 2; ++r) {
            int c = (r * 4 + wave) * 64 + lane;
            int row = c >> 2, kc = c & 3;
            gld_lds16((char*)sA + (size_t)(r * 4 + wave) * 1024,
                      A + (size_t)(bm + row) * K + k0 + kc * 8);
            gld_lds16((char*)sB + (size_t)(r * 4 + wave) * 1024,
                      Bm + (size_t)(bn + row) * K + k0 + kc * 8);
        }
        __syncthreads();
        bf16x8 af[4], bfr[4];
#pragma unroll
        for (int mb = 0; mb < 4; mb++)
            af[mb] = *(const bf16x8*)(sA + (wr * 64 + mb * 16 + l16) * 32 + quad * 8);
#pragma unroll
        for (int nb = 0; nb < 4; nb++)
            bfr[nb] = *(const bf16x8*)(sB + (wc * 64 + nb * 16 + l16) * 32 + quad * 8);
#pragma unroll
        for (int mb = 0; mb < 4; mb++)
#pragma unroll
            for (int nb = 0; nb < 4; nb++)
                acc[mb][nb] = __builtin_amdgcn_mfma_f32_16x16x32_bf16(af[mb], bfr[nb], acc[mb][nb], 0, 0, 0);
        __syncthreads();
    }
#pragma unroll
    for (int mb = 0; mb < 4; mb++)
#pragma unroll
        for (int nb = 0; nb < 4; nb++) {
            int col = bn + wc * 64 + nb * 16 + l16;
            float bv = bias ? bias[col] : 0.f;
#pragma unroll
            for (int r = 0; r < 4; r++) {
                int row = bm + wr * 64 + mb * 16 + quad * 4 + r;
                C[(size_t)row * N + col] = acc[mb][nb][r] + bv;
            }
        }
}

// ---------------------------------------------------------------------------
// prep = fused RoPE(q,k) + V pack. One launch, two block-uniform paths.
//
// K packed FRAGMENT-MAJOR per 64-key tile:
//   k_s[bh][tile(32)][sub(8)=g*2+kc][lane(64)=quad*16+k16][j(8)]
//   element = K[key=g*16+k16][d=kc*32+quad*8+j]  -> flash reads b128 at lane*16B.
// V packed FRAGMENT-MAJOR per 32-key chunk:
//   vT[bh][chunk(64)][db(4)][lane(64)=q*16+l16][jj(8)]
//   element = V[key=chunk*32+(jj<4?4q+jj:16+4q+jj-4)][d=db*16+l16]
// q: [B,H,N,64] row-major; scale 0.125*log2e folded into q.
// ---------------------------------------------------------------------------
__global__ __launch_bounds__(256) void prep(const float* __restrict__ qkv,
                                            const float* __restrict__ voxel,
                                            const float* __restrict__ theta,
                                            const int* __restrict__ gh_p, const int* __restrict__ gw_p,
                                            u16* __restrict__ q_s, u16* __restrict__ k_s,
                                            u16* __restrict__ vT, int B, int nrope) {
    __shared__ u16 tile[64][66];
    int bid = blockIdx.x;
    int t = threadIdx.x;
    if (bid < nrope) {
        // ---- RoPE path ----
        int tid = bid * 256 + t;
        int d = tid & (DHALF - 1);
        int n = (tid >> 5) & (NTOK - 1);
        int hb = tid >> 16;  // 32*2048 = 65536 per (b,h)
        int h = hb % NHEADS;
        int b = hb / NHEADS;
        int gh = *gh_p, gw = *gw_p;
        int xw = n % gw;
        int rem = n / gw;
        int yh = rem % gh;
        int zd = rem / gh;
        int axis = d % 3;
        float coordv = (axis == 0 ? (float)zd : (axis == 1 ? (float)yh : (float)xw)) * voxel[axis];
        float ang = coordv * theta[h * DHALF + d];
        float s, c;
        __sincosf(ang, &s, &c);
        size_t bi = ((size_t)b * NTOK + n) * (3 * DIM);
        const float* qp = qkv + bi + h * HDIM;
        float q1 = qp[d], q2 = qp[d + DHALF];
        float k1 = qp[DIM + d], k2 = qp[DIM + d + DHALF];
        size_t bh = (size_t)b * NHEADS + h;
        size_t bo = (bh * NTOK + n) * HDIM;
        const float qscale = 0.125f * LOG2E;
        q_s[bo + d] = f2bf((q1 * c - q2 * s) * qscale);
        q_s[bo + d + DHALF] = f2bf((q1 * s + q2 * c) * qscale);
        int tile_i = n >> 6, r = n & 63, g = r >> 4, k16 = r & 15;
        int qd = d >> 3, j = d & 7;  // d < 32
        size_t off = bh * NTOK * HDIM + (size_t)tile_i * 4096 +
                     (size_t)(g * 2) * 512 + (qd * 16 + k16) * 8 + j;
        k_s[off] = f2bf(k1 * c - k2 * s);        // kc = 0 (dims 0..31)
        k_s[off + 512] = f2bf(k1 * s + k2 * c);  // kc = 1 (dims 32..63)
    } else {
        // ---- V pack path ----
        int idx = bid - nrope;
        int nt = idx & 31;             // NTOK/64 tiles
        int rem = idx >> 5;
        int h = rem % NHEADS, b = rem / NHEADS;
        int n_loc = t >> 2, d0 = (t & 3) * 16;
        const float* src = qkv + ((size_t)b * NTOK + nt * 64 + n_loc) * (3 * DIM) + 2 * DIM + h * HDIM + d0;
#pragma unroll
        for (int j = 0; j < 16; j += 4) {
            float4 v = *(const float4*)(src + j);
            tile[n_loc][d0 + j + 0] = f2bf(v.x);
            tile[n_loc][d0 + j + 1] = f2bf(v.y);
            tile[n_loc][d0 + j + 2] = f2bf(v.z);
            tile[n_loc][d0 + j + 3] = f2bf(v.w);
        }
        __syncthreads();
        int db = t >> 6, l = t & 63, q = (t >> 4) & 3, l16 = t & 15;
        int dd = db * 16 + l16;
        size_t bh = (size_t)b * NHEADS + h;
#pragma unroll
        for (int c = 0; c < 2; c++) {
            u32 w[4];
#pragma unroll
            for (int jp = 0; jp < 4; jp++) {
                int jj0 = jp * 2, jj1 = jp * 2 + 1;
                int key0 = c * 32 + (jj0 < 4 ? 4 * q + jj0 : 16 + 4 * q + jj0 - 4);
                int key1 = c * 32 + (jj1 < 4 ? 4 * q + jj1 : 16 + 4 * q + jj1 - 4);
                w[jp] = (u32)tile[key0][dd] | ((u32)tile[key1][dd] << 16);
            }
            u16* dst = vT + ((bh * 64 + (size_t)nt * 2 + c) * 2048 + db * 512 + (size_t)l * 8);
            *(uint4*)dst = make_uint4(w[0], w[1], w[2], w[3]);
        }
    }
}

// ---------------------------------------------------------------------------
// Flash attention v12 = v11 split-K + in-flash combine + s_setprio.
// v11 post-mortem: flash 46.4us (latency-bound, no pipe >55%), but the
// separate combine kernel + 25MB partial reads ate the split-K gain
// (pipeline 193.6 -> 195.4). v12 keeps the balanced 768-WG split-K shape
// and removes the tax:
//  - LAST-FINISHER COMBINE: both WGs of a (bh,qt) pair write f32 partials;
//    a per-pair flag (atomicAdd, device-scope per m20) elects the second
//    finisher, which re-reads only the PARTNER partial (own stays in regs),
//    normalizes, writes bf16 attn. Saves combine launch + 12.5MB reads.
//  - XCD PAIRING: bid = g*16 + ks*8 + j puts both ks-halves of a pair AND
//    all WGs of one bh on XCD bh%8 -> partner partials are L2-hot.
//    (NBH*16 units, NBH%8==0 guaranteed by NHEADS=12 w/ B even... B*12*16
//    is always divisible by 8.)
//  - T5 s_setprio(1) around S-MFMA and PV-MFMA bursts (m191: +4-7% attn).
// Flags zeroed by hipMemsetAsync each launch (graph-safe, no re-poison).
// ---------------------------------------------------------------------------
__global__ __launch_bounds__(256) void flash_attn(const u16* __restrict__ Q, const u16* __restrict__ Kp,
                                                  const u16* __restrict__ Vp, float* __restrict__ Opart,
                                                  float* __restrict__ Sums, u16* __restrict__ Out,
                                                  u32* __restrict__ flags, int NBH) {
    int bid = blockIdx.x;
    int g = bid >> 4, j = bid & 7, ks = (bid >> 3) & 1;
    int u = g * 8 + j;          // pair id in [0, NBH*16)
    int bh_i = u % NBH;
    int qt = u / NBH;           // 0..15
    int b = bh_i / NHEADS, h = bh_i % NHEADS;
    int t = threadIdx.x, wave = t >> 6, lane = t & 63, quad = lane >> 4, l16 = lane & 15;
    size_t bh = (size_t)b * NHEADS + h;
    const u16* Qb = Q + bh * NTOK * HDIM;
    const u16* Kb = Kp + bh * NTOK * HDIM;  // frag-major 4096-elem tiles
    const u16* Vb = Vp + bh * NTOK * HDIM;  // frag-major: 2 chunks x 2048 per tile

    __shared__ __align__(16) u16 smem[2][8192];  // [buf][K 4096 | V 4096] = 32KB

    const int q0 = qt * 128 + wave * 32;  // 32 q-rows per wave
    bf16x8 qf[2][2];
#pragma unroll
    for (int qb = 0; qb < 2; qb++)
#pragma unroll
        for (int kc = 0; kc < 2; kc++)
            qf[qb][kc] = *(const bf16x8*)(Qb + (size_t)(q0 + qb * 16 + l16) * HDIM + kc * 32 + quad * 8);

    // ones B-frag: col 0 accumulates the P row-sum
    s16x8 ov;
#pragma unroll
    for (int jj = 0; jj < 8; jj++) ov[jj] = (l16 == 0) ? (short)0x3F80 : (short)0;

    f32x4 o[2][5];
#pragma unroll
    for (int qb = 0; qb < 2; qb++)
#pragma unroll
        for (int db = 0; db < 5; db++) o[qb][db] = f4zero();

    // stage 8KB K + 8KB V of tile kt into buffer bi (4 x 1KB DMA per wave)
    auto stage = [&](int kt, int bi) {
        const u16* Kg = Kb + (size_t)kt * 4096;
        const u16* Vg = Vb + (size_t)kt * 4096;
        u16* buf = &smem[bi][0];
#pragma unroll
        for (int s = 0; s < 2; s++) {
            gld_lds16(buf + (wave * 2 + s) * 512, Kg + (wave * 2 + s) * 512 + lane * 8);
            gld_lds16(buf + 4096 + (wave * 2 + s) * 512, Vg + (wave * 2 + s) * 512 + lane * 8);
        }
    };

    const int kt0 = ks * (NTOK / 128);          // 16 tiles per half
    const int kt1 = kt0 + (NTOK / 128);
    stage(kt0, 0);
    int cur = 0;
    for (int kt = kt0; kt < kt1; ++kt) {
        __syncthreads();  // drains DMA of buf[cur]; protects buf[cur^1] reuse
        if (kt + 1 < kt1) stage(kt + 1, cur ^ 1);
        const u16* sK = &smem[cur][0];
        const u16* sV = &smem[cur][4096];
#pragma unroll
        for (int c = 0; c < 2; ++c) {
            bf16x8 kf[2][2];
#pragma unroll
            for (int kb2 = 0; kb2 < 2; kb2++)
#pragma unroll
                for (int kc = 0; kc < 2; kc++)
                    kf[kb2][kc] = *(const bf16x8*)(sK + ((c * 2 + kb2) * 2 + kc) * 512 + lane * 8);
            s16x8 bv[4];
#pragma unroll
            for (int db = 0; db < 4; db++)
                bv[db] = *(const s16x8*)(sV + c * 2048 + db * 512 + lane * 8);
#pragma unroll
            for (int qb = 0; qb < 2; qb++) {
                f32x4 st0, st1;
                __builtin_amdgcn_s_setprio(1);
                {
                    f32x4 z = f4zero();
                    z = __builtin_amdgcn_mfma_f32_16x16x32_bf16(kf[0][0], qf[qb][0], z, 0, 0, 0);
                    st0 = __builtin_amdgcn_mfma_f32_16x16x32_bf16(kf[0][1], qf[qb][1], z, 0, 0, 0);
                    f32x4 z2 = f4zero();
                    z2 = __builtin_amdgcn_mfma_f32_16x16x32_bf16(kf[1][0], qf[qb][0], z2, 0, 0, 0);
                    st1 = __builtin_amdgcn_mfma_f32_16x16x32_bf16(kf[1][1], qf[qb][1], z2, 0, 0, 0);
                }
                __builtin_amdgcn_s_setprio(0);
                bf16x8 pb;
#pragma unroll
                for (int r = 0; r < 4; r++) {
                    pb[r] = (__bf16)__builtin_exp2f(st0[r]);
                    pb[r + 4] = (__bf16)__builtin_exp2f(st1[r]);
                }
                __builtin_amdgcn_s_setprio(1);
#pragma unroll
                for (int db = 0; db < 4; db++)
                    o[qb][db] = __builtin_amdgcn_mfma_f32_16x16x32_bf16(pb, __builtin_bit_cast(bf16x8, bv[db]),
                                                                       o[qb][db], 0, 0, 0);
                o[qb][4] = __builtin_amdgcn_mfma_f32_16x16x32_bf16(pb, __builtin_bit_cast(bf16x8, ov),
                                                                  o[qb][4], 0, 0, 0);
                __builtin_amdgcn_s_setprio(0);
            }
        }
        cur ^= 1;
    }

    // ---- epilogue: publish partial, elect last finisher, combine in-flash ----
    float* Ob = Opart + ((size_t)ks * NBH + bh) * NTOK * HDIM;
    float* Sb = Sums + ((size_t)ks * NBH + bh) * NTOK;
#pragma unroll
    for (int qb = 0; qb < 2; qb++)
#pragma unroll
        for (int r = 0; r < 4; r++) {
            int n = q0 + qb * 16 + quad * 4 + r;
            if (l16 == 0) Sb[n] = o[qb][4][r];
            float* dst = Ob + (size_t)n * HDIM + l16;
#pragma unroll
            for (int db = 0; db < 4; db++)
                dst[db * 16] = o[qb][db][r];
        }
    __threadfence();                 // release: partial visible device-wide
    __shared__ int lastflag;
    __syncthreads();                 // all threads' stores + fences done
    if (t == 0) lastflag = (int)atomicAdd(&flags[u], 1u);
    __syncthreads();
    if (lastflag == 0) return;       // first finisher: partner combines
    __threadfence();                 // acquire: partner's partial now visible

    const float* Po = Opart + ((size_t)(ks ^ 1) * NBH + bh) * NTOK * HDIM;
    const float* Ps = Sums + ((size_t)(ks ^ 1) * NBH + bh) * NTOK;
#pragma unroll
    for (int qb = 0; qb < 2; qb++)
#pragma unroll
        for (int r = 0; r < 4; r++) {
            int n = q0 + qb * 16 + quad * 4 + r;
            float s = __shfl(o[qb][4][r], lane & 48) + Ps[n];
            float inv = 1.0f / s;
            const float* psrc = Po + (size_t)n * HDIM + l16;
            u16* dstb = Out + ((size_t)b * NTOK + n) * DIM + h * HDIM + l16;
#pragma unroll
            for (int db = 0; db < 4; db++)
                dstb[db * 16] = f2bf((o[qb][db][r] + psrc[db * 16]) * inv);
        }
}

// ---------------------------------------------------------------------------
extern "C" void kernel_launch(void* const* d_in, const int* in_sizes, int n_in,
                              void* d_out, int out_size, void* d_ws, size_t ws_size,
                              hipStream_t stream) {
    const float* x = (const float*)d_in[0];
    const float* voxel = (const float*)d_in[1];
    const float* w_qkv = (const float*)d_in[2];
    const float* w_proj = (const float*)d_in[3];
    const float* b_proj = (const float*)d_in[4];
    const float* theta = (const float*)d_in[5];
    const int* gh_p = (const int*)d_in[7];
    const int* gw_p = (const int*)d_in[8];
    const int B = in_sizes[0] / (NTOK * DIM);
    const int M = B * NTOK;
    const int NBH = B * NHEADS;

    char* p = (char*)d_ws;
    u16* xb = (u16*)p;       p += (size_t)M * DIM * 2;
    u16* wqkvb = (u16*)p;    p += (size_t)3 * DIM * DIM * 2;
    u16* wprojb = (u16*)p;   p += (size_t)DIM * DIM * 2;
    float* qkv = (float*)p;  p += (size_t)M * 3 * DIM * 4;
    u16* q_s = (u16*)p;      p += (size_t)M * DIM * 2;
    u16* k_s = (u16*)p;      p += (size_t)M * DIM * 2;
    u16* vT = (u16*)p;       p += (size_t)M * DIM * 2;
    u16* attn = (u16*)p;     p += (size_t)M * DIM * 2;
    u32* flags = (u32*)p;    p += (size_t)NBH * 16 * 4;

    // split-K partials alias the qkv buffer (dead after prep):
    // 2*NBH*NTOK*HDIM + 2*NBH*NTOK floats = 25.6MB < 37.7MB (per-B ratio safe)
    float* opart = qkv;
    float* sums = qkv + (size_t)2 * NBH * NTOK * HDIM;

    int na4 = M * DIM / 4, nb4 = 3 * DIM * DIM / 4, nc4 = DIM * DIM / 4;
    cast3_f32_to_bf16<<<dim3((na4 + nb4 + nc4 + 255) / 256), 256, 0, stream>>>(
        x, xb, na4, w_qkv, wqkvb, nb4, w_proj, wprojb, nc4);

    gemm_bt<<<dim3(3 * DIM / 128, M / 128), 256, 0, stream>>>(xb, wqkvb, qkv, nullptr, M, 3 * DIM, DIM);

    int nrope = (B * NHEADS * NTOK * DHALF) / 256;
    int nvt = B * NHEADS * (NTOK / 64);
    prep<<<dim3(nrope + nvt), 256, 0, stream>>>(qkv, voxel, theta, gh_p, gw_p, q_s, k_s, vT, B, nrope);

    // zero the pair-election flags (1.5KB; graph-capture-safe)
    hipMemsetAsync(flags, 0, (size_t)NBH * 16 * 4, stream);

    // grid = NBH*16 pairs x 2 key-halves = 768 for B=2 -> exactly 3 WG/CU
    flash_attn<<<dim3(NBH * 32), 256, 0, stream>>>(q_s, k_s, vT, opart, sums, attn, flags, NBH);

    gemm_bt<<<dim3(DIM / 128, M / 128), 256, 0, stream>>>(attn, wprojb, (float*)d_out, b_proj, M, DIM, DIM);
}

// Round 4
// 190.484 us; speedup vs baseline: 1.7844x; 1.7844x over previous
//
#include <hip/hip_runtime.h>
#include <stdint.h>

#define DIM 768
#define NHEADS 12
#define HDIM 64
#define DHALF 32
#define NTOK 2048
#define LOG2E 1.44269504088896340736f

typedef unsigned short u16;
typedef unsigned int u32;
typedef __bf16 bf16x8 __attribute__((ext_vector_type(8)));
typedef short s16x8 __attribute__((ext_vector_type(8)));
typedef float f32x4 __attribute__((ext_vector_type(4)));

__device__ __forceinline__ f32x4 f4zero() { f32x4 z = {0.f, 0.f, 0.f, 0.f}; return z; }

// fp32 -> bf16 bits, round-to-nearest-even
__device__ __forceinline__ u16 f2bf(float f) {
    u32 u = __builtin_bit_cast(u32, f);
    u32 r = (u + 0x7FFFu + ((u >> 16) & 1u)) >> 16;
    return (u16)r;
}

// async global->LDS, 16B per lane. LDS dest = wave-uniform base + lane*16.
__device__ __forceinline__ void gld_lds16(void* lds, const void* g) {
    __builtin_amdgcn_global_load_lds((const __attribute__((address_space(1))) u32*)g,
                                     (__attribute__((address_space(3))) u32*)lds,
                                     16, 0, 0);
}

// ---------------------------------------------------------------------------
// fused fp32 -> bf16 cast of x, w_qkv, w_proj (one launch)
// ---------------------------------------------------------------------------
__global__ __launch_bounds__(256) void cast3_f32_to_bf16(const float* __restrict__ a, u16* __restrict__ oa, int na4,
                                                         const float* __restrict__ b, u16* __restrict__ ob, int nb4,
                                                         const float* __restrict__ c, u16* __restrict__ oc, int nc4) {
    int i = blockIdx.x * 256 + threadIdx.x;
    const float* src;
    u16* dst;
    int j = i;
    if (i < na4) { src = a; dst = oa; }
    else if (i < na4 + nb4) { src = b; dst = ob; j = i - na4; }
    else if (i < na4 + nb4 + nc4) { src = c; dst = oc; j = i - na4 - nb4; }
    else return;
    float4 v = ((const float4*)src)[j];
    u32 w0 = (u32)f2bf(v.x) | ((u32)f2bf(v.y) << 16);
    u32 w1 = (u32)f2bf(v.z) | ((u32)f2bf(v.w) << 16);
    ((uint2*)dst)[j] = make_uint2(w0, w1);
}

// ---------------------------------------------------------------------------
// bt-GEMM v2: C[M,N] = A[M,K] * B[N,K]^T (+bias), bf16 in, fp32 out.
// 128x128 tile, BK=32, 256 threads = 2x2 waves, each wave 64x64 (4x4 MFMA).
// R4 change: DOUBLE-BUFFERED global_load_lds (T3-minimal 2-phase, same
// pattern as flash_attn): stage tile k+1 right after the barrier so its DMA
// overlaps the whole compute of tile k. Previous version staged immediately
// before the vmcnt(0)-draining barrier -> DMA latency fully exposed on every
// one of the K/32 iterations. LDS 16->32KB (still 5 WG/CU capacity).
// ---------------------------------------------------------------------------
__global__ __launch_bounds__(256) void gemm_bt(const u16* __restrict__ A, const u16* __restrict__ Bm,
                                               float* __restrict__ C, const float* __restrict__ bias,
                                               int M, int N, int K) {
    __shared__ __align__(16) u16 sA[2][128 * 32];
    __shared__ __align__(16) u16 sB[2][128 * 32];
    const int t = threadIdx.x;
    const int wave = t >> 6, lane = t & 63;
    const int quad = lane >> 4, l16 = lane & 15;
    const int bm = blockIdx.y * 128, bn = blockIdx.x * 128;
    const int wr = wave >> 1, wc = wave & 1;

    f32x4 acc[4][4];
#pragma unroll
    for (int i = 0; i < 4; i++)
#pragma unroll
        for (int j = 0; j < 4; j++) acc[i][j] = f4zero();

    // stage one 128x32 A-tile + B-tile at k0 into buffer bi (4 DMA/wave)
    auto stage = [&](int k0, int bi) {
#pragma unroll
        for (int r = 0; r < 2; ++r) {
            int c = (r * 4 + wave) * 64 + lane;
            int row = c >> 2, kc = c & 3;
            gld_lds16((char*)&sA[bi][0] + (size_t)(r * 4 + wave) * 1024,
                      A + (size_t)(bm + row) * K + k0 + kc * 8);
            gld_lds16((char*)&sB[bi][0] + (size_t)(r * 4 + wave) * 1024,
                      Bm + (size_t)(bn + row) * K + k0 + kc * 8);
        }
    };

    stage(0, 0);
    int cur = 0;
    for (int k0 = 0; k0 < K; k0 += 32) {
        __syncthreads();  // drains DMA of buf[cur]; protects buf[cur^1] reuse
        if (k0 + 32 < K) stage(k0 + 32, cur ^ 1);
        const u16* pA = &sA[cur][0];
        const u16* pB = &sB[cur][0];
        bf16x8 af[4], bfr[4];
#pragma unroll
        for (int mb = 0; mb < 4; mb++)
            af[mb] = *(const bf16x8*)(pA + (wr * 64 + mb * 16 + l16) * 32 + quad * 8);
#pragma unroll
        for (int nb = 0; nb < 4; nb++)
            bfr[nb] = *(const bf16x8*)(pB + (wc * 64 + nb * 16 + l16) * 32 + quad * 8);
#pragma unroll
        for (int mb = 0; mb < 4; mb++)
#pragma unroll
            for (int nb = 0; nb < 4; nb++)
                acc[mb][nb] = __builtin_amdgcn_mfma_f32_16x16x32_bf16(af[mb], bfr[nb], acc[mb][nb], 0, 0, 0);
        cur ^= 1;
    }
#pragma unroll
    for (int mb = 0; mb < 4; mb++)
#pragma unroll
        for (int nb = 0; nb < 4; nb++) {
            int col = bn + wc * 64 + nb * 16 + l16;
            float bv = bias ? bias[col] : 0.f;
#pragma unroll
            for (int r = 0; r < 4; r++) {
                int row = bm + wr * 64 + mb * 16 + quad * 4 + r;
                C[(size_t)row * N + col] = acc[mb][nb][r] + bv;
            }
        }
}

// ---------------------------------------------------------------------------
// prep = fused RoPE(q,k) + V pack. One launch, two block-uniform paths.
//
// K packed FRAGMENT-MAJOR per 64-key tile:
//   k_s[bh][tile(32)][sub(8)=g*2+kc][lane(64)=quad*16+k16][j(8)]
//   element = K[key=g*16+k16][d=kc*32+quad*8+j]  -> flash reads b128 at lane*16B.
// V packed FRAGMENT-MAJOR per 32-key chunk:
//   vT[bh][chunk(64)][db(4)][lane(64)=q*16+l16][jj(8)]
//   element = V[key=chunk*32+(jj<4?4q+jj:16+4q+jj-4)][d=db*16+l16]
// q: [B,H,N,64] row-major; scale 0.125*log2e folded into q.
// ---------------------------------------------------------------------------
__global__ __launch_bounds__(256) void prep(const float* __restrict__ qkv,
                                            const float* __restrict__ voxel,
                                            const float* __restrict__ theta,
                                            const int* __restrict__ gh_p, const int* __restrict__ gw_p,
                                            u16* __restrict__ q_s, u16* __restrict__ k_s,
                                            u16* __restrict__ vT, int B, int nrope) {
    __shared__ u16 tile[64][66];
    int bid = blockIdx.x;
    int t = threadIdx.x;
    if (bid < nrope) {
        // ---- RoPE path ----
        int tid = bid * 256 + t;
        int d = tid & (DHALF - 1);
        int n = (tid >> 5) & (NTOK - 1);
        int hb = tid >> 16;  // 32*2048 = 65536 per (b,h)
        int h = hb % NHEADS;
        int b = hb / NHEADS;
        int gh = *gh_p, gw = *gw_p;
        int xw = n % gw;
        int rem = n / gw;
        int yh = rem % gh;
        int zd = rem / gh;
        int axis = d % 3;
        float coordv = (axis == 0 ? (float)zd : (axis == 1 ? (float)yh : (float)xw)) * voxel[axis];
        float ang = coordv * theta[h * DHALF + d];
        float s, c;
        __sincosf(ang, &s, &c);
        size_t bi = ((size_t)b * NTOK + n) * (3 * DIM);
        const float* qp = qkv + bi + h * HDIM;
        float q1 = qp[d], q2 = qp[d + DHALF];
        float k1 = qp[DIM + d], k2 = qp[DIM + d + DHALF];
        size_t bh = (size_t)b * NHEADS + h;
        size_t bo = (bh * NTOK + n) * HDIM;
        const float qscale = 0.125f * LOG2E;
        q_s[bo + d] = f2bf((q1 * c - q2 * s) * qscale);
        q_s[bo + d + DHALF] = f2bf((q1 * s + q2 * c) * qscale);
        int tile_i = n >> 6, r = n & 63, g = r >> 4, k16 = r & 15;
        int qd = d >> 3, j = d & 7;  // d < 32
        size_t off = bh * NTOK * HDIM + (size_t)tile_i * 4096 +
                     (size_t)(g * 2) * 512 + (qd * 16 + k16) * 8 + j;
        k_s[off] = f2bf(k1 * c - k2 * s);        // kc = 0 (dims 0..31)
        k_s[off + 512] = f2bf(k1 * s + k2 * c);  // kc = 1 (dims 32..63)
    } else {
        // ---- V pack path ----
        int idx = bid - nrope;
        int nt = idx & 31;             // NTOK/64 tiles
        int rem = idx >> 5;
        int h = rem % NHEADS, b = rem / NHEADS;
        int n_loc = t >> 2, d0 = (t & 3) * 16;
        const float* src = qkv + ((size_t)b * NTOK + nt * 64 + n_loc) * (3 * DIM) + 2 * DIM + h * HDIM + d0;
#pragma unroll
        for (int j = 0; j < 16; j += 4) {
            float4 v = *(const float4*)(src + j);
            tile[n_loc][d0 + j + 0] = f2bf(v.x);
            tile[n_loc][d0 + j + 1] = f2bf(v.y);
            tile[n_loc][d0 + j + 2] = f2bf(v.z);
            tile[n_loc][d0 + j + 3] = f2bf(v.w);
        }
        __syncthreads();
        int db = t >> 6, l = t & 63, q = (t >> 4) & 3, l16 = t & 15;
        int dd = db * 16 + l16;
        size_t bh = (size_t)b * NHEADS + h;
#pragma unroll
        for (int c = 0; c < 2; c++) {
            u32 w[4];
#pragma unroll
            for (int jp = 0; jp < 4; jp++) {
                int jj0 = jp * 2, jj1 = jp * 2 + 1;
                int key0 = c * 32 + (jj0 < 4 ? 4 * q + jj0 : 16 + 4 * q + jj0 - 4);
                int key1 = c * 32 + (jj1 < 4 ? 4 * q + jj1 : 16 + 4 * q + jj1 - 4);
                w[jp] = (u32)tile[key0][dd] | ((u32)tile[key1][dd] << 16);
            }
            u16* dst = vT + ((bh * 64 + (size_t)nt * 2 + c) * 2048 + db * 512 + (size_t)l * 8);
            *(uint4*)dst = make_uint4(w[0], w[1], w[2], w[3]);
        }
    }
}

// ---------------------------------------------------------------------------
// Flash attention v10 (REVERT to the measured-best variant, R1: 52.2us):
// 4 waves x 16 q-rows = 64 rows/WG; grid = 768 = EXACTLY 3 WG/CU, 12
// waves/CU. R3's in-flash split-K combine (device-scope __threadfence +
// atomic election) was a 4x regression: agent-scope fences from finishing
// WGs invalidated L2 under the feet of still-running WGs (FETCH +67%, both
// pipes <14%). No mid-kernel device fences; no setprio (unattributed risk).
// Fragment-major K/V: every ds_read_b128 at base+lane*16 -> zero bank
// conflicts. All-register P path (S^T = K*Q^T; exp2; feed PV as A-frag),
// ones-column row-sum MFMA, fixed-base softmax.
// ---------------------------------------------------------------------------
__global__ __launch_bounds__(256) void flash_attn(const u16* __restrict__ Q, const u16* __restrict__ Kp,
                                                  const u16* __restrict__ Vp, u16* __restrict__ Out, int NBH) {
    int i = blockIdx.x;
    int bh_i = i % NBH;   // all of a bh's WGs land on XCD bh%8 (24%8==0)
    int qt = i / NBH;     // 0..31
    int b = bh_i / NHEADS, h = bh_i % NHEADS;
    int t = threadIdx.x, wave = t >> 6, lane = t & 63, quad = lane >> 4, l16 = lane & 15;
    size_t bh = (size_t)b * NHEADS + h;
    const u16* Qb = Q + bh * NTOK * HDIM;
    const u16* Kb = Kp + bh * NTOK * HDIM;  // frag-major 4096-elem tiles
    const u16* Vb = Vp + bh * NTOK * HDIM;  // frag-major: 2 chunks x 2048 per tile

    __shared__ __align__(16) u16 smem[2][8192];  // [buf][K 4096 | V 4096] = 32KB

    const int q0 = qt * 64 + wave * 16;  // 16 q-rows per wave
    bf16x8 qf[2];
#pragma unroll
    for (int kc = 0; kc < 2; kc++)
        qf[kc] = *(const bf16x8*)(Qb + (size_t)(q0 + l16) * HDIM + kc * 32 + quad * 8);

    // ones B-frag: col 0 accumulates the P row-sum
    s16x8 ov;
#pragma unroll
    for (int j = 0; j < 8; j++) ov[j] = (l16 == 0) ? (short)0x3F80 : (short)0;

    f32x4 o[5];
#pragma unroll
    for (int db = 0; db < 5; db++) o[db] = f4zero();

    // stage 8KB K + 8KB V of tile kt into buffer bi (4 x 1KB DMA per wave)
    auto stage = [&](int kt, int bi) {
        const u16* Kg = Kb + (size_t)kt * 4096;
        const u16* Vg = Vb + (size_t)kt * 4096;
        u16* buf = &smem[bi][0];
#pragma unroll
        for (int s = 0; s < 2; s++) {
            gld_lds16(buf + (wave * 2 + s) * 512, Kg + (wave * 2 + s) * 512 + lane * 8);
            gld_lds16(buf + 4096 + (wave * 2 + s) * 512, Vg + (wave * 2 + s) * 512 + lane * 8);
        }
    };

    stage(0, 0);
    int cur = 0;
    for (int kt = 0; kt < NTOK / 64; ++kt) {
        __syncthreads();  // drains DMA of buf[cur]; protects buf[cur^1] reuse
        if (kt + 1 < NTOK / 64) stage(kt + 1, cur ^ 1);
        const u16* sK = &smem[cur][0];
        const u16* sV = &smem[cur][4096];
#pragma unroll
        for (int c = 0; c < 2; ++c) {
            bf16x8 kf[2][2];
#pragma unroll
            for (int kb2 = 0; kb2 < 2; kb2++)
#pragma unroll
                for (int kc = 0; kc < 2; kc++)
                    kf[kb2][kc] = *(const bf16x8*)(sK + ((c * 2 + kb2) * 2 + kc) * 512 + lane * 8);
            s16x8 bv[4];
#pragma unroll
            for (int db = 0; db < 4; db++)
                bv[db] = *(const s16x8*)(sV + c * 2048 + db * 512 + lane * 8);
            f32x4 st0, st1;
            {
                f32x4 z = f4zero();
                z = __builtin_amdgcn_mfma_f32_16x16x32_bf16(kf[0][0], qf[0], z, 0, 0, 0);
                st0 = __builtin_amdgcn_mfma_f32_16x16x32_bf16(kf[0][1], qf[1], z, 0, 0, 0);
                f32x4 z2 = f4zero();
                z2 = __builtin_amdgcn_mfma_f32_16x16x32_bf16(kf[1][0], qf[0], z2, 0, 0, 0);
                st1 = __builtin_amdgcn_mfma_f32_16x16x32_bf16(kf[1][1], qf[1], z2, 0, 0, 0);
            }
            bf16x8 pb;
#pragma unroll
            for (int r = 0; r < 4; r++) {
                pb[r] = (__bf16)__builtin_exp2f(st0[r]);
                pb[r + 4] = (__bf16)__builtin_exp2f(st1[r]);
            }
#pragma unroll
            for (int db = 0; db < 4; db++)
                o[db] = __builtin_amdgcn_mfma_f32_16x16x32_bf16(pb, __builtin_bit_cast(bf16x8, bv[db]),
                                                                o[db], 0, 0, 0);
            o[4] = __builtin_amdgcn_mfma_f32_16x16x32_bf16(pb, __builtin_bit_cast(bf16x8, ov),
                                                           o[4], 0, 0, 0);
        }
        cur ^= 1;
    }

    // epilogue: broadcast row-sum from col-0 lanes, normalize, store bf16
#pragma unroll
    for (int r = 0; r < 4; r++) {
        float s = __shfl(o[4][r], lane & 48);  // lane quad*16 holds the sum
        float inv = 1.0f / s;
        int n = q0 + quad * 4 + r;
        u16* dst = Out + ((size_t)b * NTOK + n) * DIM + h * HDIM + l16;
#pragma unroll
        for (int db = 0; db < 4; db++)
            dst[db * 16] = f2bf(o[db][r] * inv);
    }
}

// ---------------------------------------------------------------------------
extern "C" void kernel_launch(void* const* d_in, const int* in_sizes, int n_in,
                              void* d_out, int out_size, void* d_ws, size_t ws_size,
                              hipStream_t stream) {
    const float* x = (const float*)d_in[0];
    const float* voxel = (const float*)d_in[1];
    const float* w_qkv = (const float*)d_in[2];
    const float* w_proj = (const float*)d_in[3];
    const float* b_proj = (const float*)d_in[4];
    const float* theta = (const float*)d_in[5];
    const int* gh_p = (const int*)d_in[7];
    const int* gw_p = (const int*)d_in[8];
    const int B = in_sizes[0] / (NTOK * DIM);
    const int M = B * NTOK;

    char* p = (char*)d_ws;
    u16* xb = (u16*)p;       p += (size_t)M * DIM * 2;
    u16* wqkvb = (u16*)p;    p += (size_t)3 * DIM * DIM * 2;
    u16* wprojb = (u16*)p;   p += (size_t)DIM * DIM * 2;
    float* qkv = (float*)p;  p += (size_t)M * 3 * DIM * 4;
    u16* q_s = (u16*)p;      p += (size_t)M * DIM * 2;
    u16* k_s = (u16*)p;      p += (size_t)M * DIM * 2;
    u16* vT = (u16*)p;       p += (size_t)M * DIM * 2;
    u16* attn = (u16*)p;     p += (size_t)M * DIM * 2;

    int na4 = M * DIM / 4, nb4 = 3 * DIM * DIM / 4, nc4 = DIM * DIM / 4;
    cast3_f32_to_bf16<<<dim3((na4 + nb4 + nc4 + 255) / 256), 256, 0, stream>>>(
        x, xb, na4, w_qkv, wqkvb, nb4, w_proj, wprojb, nc4);

    gemm_bt<<<dim3(3 * DIM / 128, M / 128), 256, 0, stream>>>(xb, wqkvb, qkv, nullptr, M, 3 * DIM, DIM);

    int nrope = (B * NHEADS * NTOK * DHALF) / 256;
    int nvt = B * NHEADS * (NTOK / 64);
    prep<<<dim3(nrope + nvt), 256, 0, stream>>>(qkv, voxel, theta, gh_p, gw_p, q_s, k_s, vT, B, nrope);

    flash_attn<<<dim3((B * NHEADS * NTOK) / 64), 256, 0, stream>>>(q_s, k_s, vT, attn, B * NHEADS);

    gemm_bt<<<dim3(DIM / 128, M / 128), 256, 0, stream>>>(attn, wprojb, (float*)d_out, b_proj, M, DIM, DIM);
}

// Round 5
// 180.370 us; speedup vs baseline: 1.8844x; 1.0561x over previous
//
#include <hip/hip_runtime.h>
#include <stdint.h>

#define DIM 768
#define NHEADS 12
#define HDIM 64
#define DHALF 32
#define NTOK 2048
#define QKVN 2304
#define LOG2E 1.44269504088896340736f

typedef unsigned short u16;
typedef unsigned int u32;
typedef __bf16 bf16x8 __attribute__((ext_vector_type(8)));
typedef short s16x8 __attribute__((ext_vector_type(8)));
typedef float f32x4 __attribute__((ext_vector_type(4)));

__device__ __forceinline__ f32x4 f4zero() { f32x4 z = {0.f, 0.f, 0.f, 0.f}; return z; }

// fp32 -> bf16 bits, round-to-nearest-even
__device__ __forceinline__ u16 f2bf(float f) {
    u32 u = __builtin_bit_cast(u32, f);
    u32 r = (u + 0x7FFFu + ((u >> 16) & 1u)) >> 16;
    return (u16)r;
}

// async global->LDS, 16B per lane. LDS dest = wave-uniform base + lane*16.
__device__ __forceinline__ void gld_lds16(void* lds, const void* g) {
    __builtin_amdgcn_global_load_lds((const __attribute__((address_space(1))) u32*)g,
                                     (__attribute__((address_space(3))) u32*)lds,
                                     16, 0, 0);
}

// ---------------------------------------------------------------------------
// fused fp32 -> bf16 cast of x, w_qkv, w_proj (one launch)
// ---------------------------------------------------------------------------
__global__ __launch_bounds__(256) void cast3_f32_to_bf16(const float* __restrict__ a, u16* __restrict__ oa, int na4,
                                                         const float* __restrict__ b, u16* __restrict__ ob, int nb4,
                                                         const float* __restrict__ c, u16* __restrict__ oc, int nc4) {
    int i = blockIdx.x * 256 + threadIdx.x;
    const float* src;
    u16* dst;
    int j = i;
    if (i < na4) { src = a; dst = oa; }
    else if (i < na4 + nb4) { src = b; dst = ob; j = i - na4; }
    else if (i < na4 + nb4 + nc4) { src = c; dst = oc; j = i - na4 - nb4; }
    else return;
    float4 v = ((const float4*)src)[j];
    u32 w0 = (u32)f2bf(v.x) | ((u32)f2bf(v.y) << 16);
    u32 w1 = (u32)f2bf(v.z) | ((u32)f2bf(v.w) << 16);
    ((uint2*)dst)[j] = make_uint2(w0, w1);
}

// ---------------------------------------------------------------------------
// bt-GEMM (generic, used for proj): C[M,N] = A[M,K]*B[N,K]^T (+bias),
// bf16 in, fp32 out. 128x128 tile, BK=32, double-buffered global_load_lds
// (stage k+1 right after the barrier -> DMA overlaps compute of tile k).
// ---------------------------------------------------------------------------
__global__ __launch_bounds__(256) void gemm_bt(const u16* __restrict__ A, const u16* __restrict__ Bm,
                                               float* __restrict__ C, const float* __restrict__ bias,
                                               int M, int N, int K) {
    __shared__ __align__(16) u16 sA[2][128 * 32];
    __shared__ __align__(16) u16 sB[2][128 * 32];
    const int t = threadIdx.x;
    const int wave = t >> 6, lane = t & 63;
    const int quad = lane >> 4, l16 = lane & 15;
    const int bm = blockIdx.y * 128, bn = blockIdx.x * 128;
    const int wr = wave >> 1, wc = wave & 1;

    f32x4 acc[4][4];
#pragma unroll
    for (int i = 0; i < 4; i++)
#pragma unroll
        for (int j = 0; j < 4; j++) acc[i][j] = f4zero();

    auto stage = [&](int k0, int bi) {
#pragma unroll
        for (int r = 0; r < 2; ++r) {
            int c = (r * 4 + wave) * 64 + lane;
            int row = c >> 2, kc = c & 3;
            gld_lds16((char*)&sA[bi][0] + (size_t)(r * 4 + wave) * 1024,
                      A + (size_t)(bm + row) * K + k0 + kc * 8);
            gld_lds16((char*)&sB[bi][0] + (size_t)(r * 4 + wave) * 1024,
                      Bm + (size_t)(bn + row) * K + k0 + kc * 8);
        }
    };

    stage(0, 0);
    int cur = 0;
    for (int k0 = 0; k0 < K; k0 += 32) {
        __syncthreads();  // drains DMA of buf[cur]; protects buf[cur^1] reuse
        if (k0 + 32 < K) stage(k0 + 32, cur ^ 1);
        const u16* pA = &sA[cur][0];
        const u16* pB = &sB[cur][0];
        bf16x8 af[4], bfr[4];
#pragma unroll
        for (int mb = 0; mb < 4; mb++)
            af[mb] = *(const bf16x8*)(pA + (wr * 64 + mb * 16 + l16) * 32 + quad * 8);
#pragma unroll
        for (int nb = 0; nb < 4; nb++)
            bfr[nb] = *(const bf16x8*)(pB + (wc * 64 + nb * 16 + l16) * 32 + quad * 8);
#pragma unroll
        for (int mb = 0; mb < 4; mb++)
#pragma unroll
            for (int nb = 0; nb < 4; nb++)
                acc[mb][nb] = __builtin_amdgcn_mfma_f32_16x16x32_bf16(af[mb], bfr[nb], acc[mb][nb], 0, 0, 0);
        cur ^= 1;
    }
#pragma unroll
    for (int mb = 0; mb < 4; mb++)
#pragma unroll
        for (int nb = 0; nb < 4; nb++) {
            int col = bn + wc * 64 + nb * 16 + l16;
            float bv = bias ? bias[col] : 0.f;
#pragma unroll
            for (int r = 0; r < 4; r++) {
                int row = bm + wr * 64 + mb * 16 + quad * 4 + r;
                C[(size_t)row * N + col] = acc[mb][nb][r] + bv;
            }
        }
}

// ---------------------------------------------------------------------------
// R5: QKV-GEMM with FUSED RoPE + flash-layout epilogue. Replaces the old
// gemm_bt(QKV) + prep pair: the epilogue register tiling already holds both
// halves of every RoPE pair in ONE thread (cols nb*16+l16: nb & nb+2 give
// d and d+32), and rows mb*16+quad*4+r are exactly the 8 keys of a vT
// fragment chunk -> V pack is a register-local uint4 store. Eliminates the
// 37.7MB f32 qkv write + prep's 37.7MB read + 18.9MB write + one launch.
//
// Block-uniform type: bn 0-5 = Q, 6-11 = K, 12-17 = V; each wave's 64-col
// window is one head h = (col0 % 768)/64.
//  Q: RoPE, scale 0.125*log2e, row-major q_s[bh][n][64].
//  K: RoPE, fragment-major k_s (same formula as old prep; verified:
//     g=mb, k16=quad*4+r, qd=nb*2+(l16>>3), j=l16&7, kc=pair-half).
//  V: vT[bh][chunk=nt*2+c][db=nb][lane][jj] with jj 0-3 = acc[2c][nb][r],
//     jj 4-7 = acc[2c+1][nb][r] -> one uint4 per (c,nb), coalesced.
// ---------------------------------------------------------------------------
__global__ __launch_bounds__(256) void gemm_qkv_rope(const u16* __restrict__ A, const u16* __restrict__ Bm,
                                                     const float* __restrict__ voxel,
                                                     const float* __restrict__ theta,
                                                     const int* __restrict__ gh_p, const int* __restrict__ gw_p,
                                                     u16* __restrict__ q_s, u16* __restrict__ k_s,
                                                     u16* __restrict__ vT, int M) {
    __shared__ __align__(16) u16 sA[2][128 * 32];
    __shared__ __align__(16) u16 sB[2][128 * 32];
    const int t = threadIdx.x;
    const int wave = t >> 6, lane = t & 63;
    const int quad = lane >> 4, l16 = lane & 15;
    const int bm = blockIdx.y * 128, bn = blockIdx.x * 128;
    const int wr = wave >> 1, wc = wave & 1;
    const int K = DIM;

    f32x4 acc[4][4];
#pragma unroll
    for (int i = 0; i < 4; i++)
#pragma unroll
        for (int j = 0; j < 4; j++) acc[i][j] = f4zero();

    auto stage = [&](int k0, int bi) {
#pragma unroll
        for (int r = 0; r < 2; ++r) {
            int c = (r * 4 + wave) * 64 + lane;
            int row = c >> 2, kc = c & 3;
            gld_lds16((char*)&sA[bi][0] + (size_t)(r * 4 + wave) * 1024,
                      A + (size_t)(bm + row) * K + k0 + kc * 8);
            gld_lds16((char*)&sB[bi][0] + (size_t)(r * 4 + wave) * 1024,
                      Bm + (size_t)(bn + row) * K + k0 + kc * 8);
        }
    };

    stage(0, 0);
    int cur = 0;
    for (int k0 = 0; k0 < K; k0 += 32) {
        __syncthreads();
        if (k0 + 32 < K) stage(k0 + 32, cur ^ 1);
        const u16* pA = &sA[cur][0];
        const u16* pB = &sB[cur][0];
        bf16x8 af[4], bfr[4];
#pragma unroll
        for (int mb = 0; mb < 4; mb++)
            af[mb] = *(const bf16x8*)(pA + (wr * 64 + mb * 16 + l16) * 32 + quad * 8);
#pragma unroll
        for (int nb = 0; nb < 4; nb++)
            bfr[nb] = *(const bf16x8*)(pB + (wc * 64 + nb * 16 + l16) * 32 + quad * 8);
#pragma unroll
        for (int mb = 0; mb < 4; mb++)
#pragma unroll
            for (int nb = 0; nb < 4; nb++)
                acc[mb][nb] = __builtin_amdgcn_mfma_f32_16x16x32_bf16(af[mb], bfr[nb], acc[mb][nb], 0, 0, 0);
        cur ^= 1;
    }

    // ---------------- fused epilogue ----------------
    const int col0 = bn + wc * 64;          // wave's 64-col window (one head)
    const int typ = col0 / DIM;             // 0=Q, 1=K, 2=V (block-uniform)
    const int h = (col0 % DIM) >> 6;
    const int b = bm / NTOK;                // 128 | NTOK -> uniform
    const int n0 = (bm % NTOK) + wr * 64;   // wave's token base (mult of 64)
    const size_t bh = (size_t)b * NHEADS + h;

    if (typ == 2) {
        // ---- V: register-local fragment-major pack ----
        int nt = n0 >> 6;
        u16* base = vT + (bh * 64 + (size_t)nt * 2) * 2048;
#pragma unroll
        for (int c2 = 0; c2 < 2; c2++)
#pragma unroll
            for (int nb = 0; nb < 4; nb++) {
                u32 w0 = (u32)f2bf(acc[2 * c2][nb][0]) | ((u32)f2bf(acc[2 * c2][nb][1]) << 16);
                u32 w1 = (u32)f2bf(acc[2 * c2][nb][2]) | ((u32)f2bf(acc[2 * c2][nb][3]) << 16);
                u32 w2 = (u32)f2bf(acc[2 * c2 + 1][nb][0]) | ((u32)f2bf(acc[2 * c2 + 1][nb][1]) << 16);
                u32 w3 = (u32)f2bf(acc[2 * c2 + 1][nb][2]) | ((u32)f2bf(acc[2 * c2 + 1][nb][3]) << 16);
                *(uint4*)(base + (size_t)c2 * 2048 + nb * 512 + lane * 8) = make_uint4(w0, w1, w2, w3);
            }
    } else {
        // ---- Q/K: in-register RoPE ----
        const int gh = *gh_p, gw = *gw_p;
        const float qsc = (typ == 0) ? 0.125f * LOG2E : 1.0f;
        const float th0 = theta[h * DHALF + l16];
        const float th1 = theta[h * DHALF + 16 + l16];
        const int ax0 = l16 % 3, ax1 = (16 + l16) % 3;
        const float vx0 = voxel[ax0], vx1 = voxel[ax1];
#pragma unroll
        for (int mb = 0; mb < 4; mb++)
#pragma unroll
            for (int r = 0; r < 4; r++) {
                int n = n0 + mb * 16 + quad * 4 + r;
                int xw = n % gw;
                int rem = n / gw;
                int yh = rem % gh;
                int zd = rem / gh;
                float c0 = (float)(ax0 == 0 ? zd : (ax0 == 1 ? yh : xw)) * vx0;
                float c1 = (float)(ax1 == 0 ? zd : (ax1 == 1 ? yh : xw)) * vx1;
                float s0, co0, s1, co1;
                __sincosf(c0 * th0, &s0, &co0);
                __sincosf(c1 * th1, &s1, &co1);
                float t1a = acc[mb][0][r], t2a = acc[mb][2][r];
                float o1a = (t1a * co0 - t2a * s0) * qsc, o2a = (t1a * s0 + t2a * co0) * qsc;
                float t1b = acc[mb][1][r], t2b = acc[mb][3][r];
                float o1b = (t1b * co1 - t2b * s1) * qsc, o2b = (t1b * s1 + t2b * co1) * qsc;
                if (typ == 0) {
                    u16* dq = q_s + (bh * NTOK + n) * HDIM;
                    dq[l16] = f2bf(o1a);
                    dq[l16 + DHALF] = f2bf(o2a);
                    dq[16 + l16] = f2bf(o1b);
                    dq[48 + l16] = f2bf(o2b);
                } else {
                    // fragment-major K (matches flash's kf read pattern)
                    int tile_i = n >> 6;
                    int k16 = quad * 4 + r;
                    size_t baseo = bh * (size_t)NTOK * HDIM + (size_t)tile_i * 4096 + mb * 1024;
                    int j = l16 & 7;
                    size_t oa = baseo + (size_t)(((l16 >> 3) * 16 + k16) * 8 + j);
                    size_t ob = baseo + (size_t)((((2 + (l16 >> 3)) * 16) + k16) * 8 + j);
                    k_s[oa] = f2bf(o1a);
                    k_s[oa + 512] = f2bf(o2a);
                    k_s[ob] = f2bf(o1b);
                    k_s[ob + 512] = f2bf(o2b);
                }
            }
    }
}

// ---------------------------------------------------------------------------
// Flash attention v10 (measured-best: R1 52.2us / R4 53.8us, unchanged):
// 4 waves x 16 q-rows = 64 rows/WG; grid = 768 = EXACTLY 3 WG/CU, 12
// waves/CU. Fragment-major K/V: every ds_read_b128 at base+lane*16 -> zero
// bank conflicts. All-register P path (S^T = K*Q^T; exp2; feed PV as
// A-frag), ones-column row-sum MFMA, fixed-base softmax.
// ---------------------------------------------------------------------------
__global__ __launch_bounds__(256) void flash_attn(const u16* __restrict__ Q, const u16* __restrict__ Kp,
                                                  const u16* __restrict__ Vp, u16* __restrict__ Out, int NBH) {
    int i = blockIdx.x;
    int bh_i = i % NBH;   // all of a bh's WGs land on XCD bh%8 (24%8==0)
    int qt = i / NBH;     // 0..31
    int b = bh_i / NHEADS, h = bh_i % NHEADS;
    int t = threadIdx.x, wave = t >> 6, lane = t & 63, quad = lane >> 4, l16 = lane & 15;
    size_t bh = (size_t)b * NHEADS + h;
    const u16* Qb = Q + bh * NTOK * HDIM;
    const u16* Kb = Kp + bh * NTOK * HDIM;  // frag-major 4096-elem tiles
    const u16* Vb = Vp + bh * NTOK * HDIM;  // frag-major: 2 chunks x 2048 per tile

    __shared__ __align__(16) u16 smem[2][8192];  // [buf][K 4096 | V 4096] = 32KB

    const int q0 = qt * 64 + wave * 16;  // 16 q-rows per wave
    bf16x8 qf[2];
#pragma unroll
    for (int kc = 0; kc < 2; kc++)
        qf[kc] = *(const bf16x8*)(Qb + (size_t)(q0 + l16) * HDIM + kc * 32 + quad * 8);

    // ones B-frag: col 0 accumulates the P row-sum
    s16x8 ov;
#pragma unroll
    for (int j = 0; j < 8; j++) ov[j] = (l16 == 0) ? (short)0x3F80 : (short)0;

    f32x4 o[5];
#pragma unroll
    for (int db = 0; db < 5; db++) o[db] = f4zero();

    // stage 8KB K + 8KB V of tile kt into buffer bi (4 x 1KB DMA per wave)
    auto stage = [&](int kt, int bi) {
        const u16* Kg = Kb + (size_t)kt * 4096;
        const u16* Vg = Vb + (size_t)kt * 4096;
        u16* buf = &smem[bi][0];
#pragma unroll
        for (int s = 0; s < 2; s++) {
            gld_lds16(buf + (wave * 2 + s) * 512, Kg + (wave * 2 + s) * 512 + lane * 8);
            gld_lds16(buf + 4096 + (wave * 2 + s) * 512, Vg + (wave * 2 + s) * 512 + lane * 8);
        }
    };

    stage(0, 0);
    int cur = 0;
    for (int kt = 0; kt < NTOK / 64; ++kt) {
        __syncthreads();  // drains DMA of buf[cur]; protects buf[cur^1] reuse
        if (kt + 1 < NTOK / 64) stage(kt + 1, cur ^ 1);
        const u16* sK = &smem[cur][0];
        const u16* sV = &smem[cur][4096];
#pragma unroll
        for (int c = 0; c < 2; ++c) {
            bf16x8 kf[2][2];
#pragma unroll
            for (int kb2 = 0; kb2 < 2; kb2++)
#pragma unroll
                for (int kc = 0; kc < 2; kc++)
                    kf[kb2][kc] = *(const bf16x8*)(sK + ((c * 2 + kb2) * 2 + kc) * 512 + lane * 8);
            s16x8 bv[4];
#pragma unroll
            for (int db = 0; db < 4; db++)
                bv[db] = *(const s16x8*)(sV + c * 2048 + db * 512 + lane * 8);
            f32x4 st0, st1;
            {
                f32x4 z = f4zero();
                z = __builtin_amdgcn_mfma_f32_16x16x32_bf16(kf[0][0], qf[0], z, 0, 0, 0);
                st0 = __builtin_amdgcn_mfma_f32_16x16x32_bf16(kf[0][1], qf[1], z, 0, 0, 0);
                f32x4 z2 = f4zero();
                z2 = __builtin_amdgcn_mfma_f32_16x16x32_bf16(kf[1][0], qf[0], z2, 0, 0, 0);
                st1 = __builtin_amdgcn_mfma_f32_16x16x32_bf16(kf[1][1], qf[1], z2, 0, 0, 0);
            }
            bf16x8 pb;
#pragma unroll
            for (int r = 0; r < 4; r++) {
                pb[r] = (__bf16)__builtin_exp2f(st0[r]);
                pb[r + 4] = (__bf16)__builtin_exp2f(st1[r]);
            }
#pragma unroll
            for (int db = 0; db < 4; db++)
                o[db] = __builtin_amdgcn_mfma_f32_16x16x32_bf16(pb, __builtin_bit_cast(bf16x8, bv[db]),
                                                                o[db], 0, 0, 0);
            o[4] = __builtin_amdgcn_mfma_f32_16x16x32_bf16(pb, __builtin_bit_cast(bf16x8, ov),
                                                           o[4], 0, 0, 0);
        }
        cur ^= 1;
    }

    // epilogue: broadcast row-sum from col-0 lanes, normalize, store bf16
#pragma unroll
    for (int r = 0; r < 4; r++) {
        float s = __shfl(o[4][r], lane & 48);  // lane quad*16 holds the sum
        float inv = 1.0f / s;
        int n = q0 + quad * 4 + r;
        u16* dst = Out + ((size_t)b * NTOK + n) * DIM + h * HDIM + l16;
#pragma unroll
        for (int db = 0; db < 4; db++)
            dst[db * 16] = f2bf(o[db][r] * inv);
    }
}

// ---------------------------------------------------------------------------
extern "C" void kernel_launch(void* const* d_in, const int* in_sizes, int n_in,
                              void* d_out, int out_size, void* d_ws, size_t ws_size,
                              hipStream_t stream) {
    const float* x = (const float*)d_in[0];
    const float* voxel = (const float*)d_in[1];
    const float* w_qkv = (const float*)d_in[2];
    const float* w_proj = (const float*)d_in[3];
    const float* b_proj = (const float*)d_in[4];
    const float* theta = (const float*)d_in[5];
    const int* gh_p = (const int*)d_in[7];
    const int* gw_p = (const int*)d_in[8];
    const int B = in_sizes[0] / (NTOK * DIM);
    const int M = B * NTOK;

    char* p = (char*)d_ws;
    u16* xb = (u16*)p;       p += (size_t)M * DIM * 2;
    u16* wqkvb = (u16*)p;    p += (size_t)3 * DIM * DIM * 2;
    u16* wprojb = (u16*)p;   p += (size_t)DIM * DIM * 2;
    u16* q_s = (u16*)p;      p += (size_t)M * DIM * 2;
    u16* k_s = (u16*)p;      p += (size_t)M * DIM * 2;
    u16* vT = (u16*)p;       p += (size_t)M * DIM * 2;
    u16* attn = (u16*)p;     p += (size_t)M * DIM * 2;

    int na4 = M * DIM / 4, nb4 = 3 * DIM * DIM / 4, nc4 = DIM * DIM / 4;
    cast3_f32_to_bf16<<<dim3((na4 + nb4 + nc4 + 255) / 256), 256, 0, stream>>>(
        x, xb, na4, w_qkv, wqkvb, nb4, w_proj, wprojb, nc4);

    // QKV GEMM with fused RoPE + flash-layout epilogue (replaces gemm+prep)
    gemm_qkv_rope<<<dim3(QKVN / 128, M / 128), 256, 0, stream>>>(
        xb, wqkvb, voxel, theta, gh_p, gw_p, q_s, k_s, vT, M);

    flash_attn<<<dim3((B * NHEADS * NTOK) / 64), 256, 0, stream>>>(q_s, k_s, vT, attn, B * NHEADS);

    gemm_bt<<<dim3(DIM / 128, M / 128), 256, 0, stream>>>(attn, wprojb, (float*)d_out, b_proj, M, DIM, DIM);
}

// Round 6
// 176.595 us; speedup vs baseline: 1.9247x; 1.0214x over previous
//
#include <hip/hip_runtime.h>
#include <stdint.h>

#define DIM 768
#define NHEADS 12
#define HDIM 64
#define DHALF 32
#define NTOK 2048
#define QKVN 2304
#define LOG2E 1.44269504088896340736f

typedef unsigned short u16;
typedef unsigned int u32;
typedef __bf16 bf16x8 __attribute__((ext_vector_type(8)));
typedef short s16x8 __attribute__((ext_vector_type(8)));
typedef float f32x4 __attribute__((ext_vector_type(4)));

__device__ __forceinline__ f32x4 f4zero() { f32x4 z = {0.f, 0.f, 0.f, 0.f}; return z; }

// fp32 -> bf16 bits, round-to-nearest-even
__device__ __forceinline__ u16 f2bf(float f) {
    u32 u = __builtin_bit_cast(u32, f);
    u32 r = (u + 0x7FFFu + ((u >> 16) & 1u)) >> 16;
    return (u16)r;
}

// async global->LDS, 16B per lane. LDS dest = wave-uniform base + lane*16.
__device__ __forceinline__ void gld_lds16(void* lds, const void* g) {
    __builtin_amdgcn_global_load_lds((const __attribute__((address_space(1))) u32*)g,
                                     (__attribute__((address_space(3))) u32*)lds,
                                     16, 0, 0);
}

// ---------------------------------------------------------------------------
// fused fp32 -> bf16 cast of x, w_qkv, w_proj (one launch)
// ---------------------------------------------------------------------------
__global__ __launch_bounds__(256) void cast3_f32_to_bf16(const float* __restrict__ a, u16* __restrict__ oa, int na4,
                                                         const float* __restrict__ b, u16* __restrict__ ob, int nb4,
                                                         const float* __restrict__ c, u16* __restrict__ oc, int nc4) {
    int i = blockIdx.x * 256 + threadIdx.x;
    const float* src;
    u16* dst;
    int j = i;
    if (i < na4) { src = a; dst = oa; }
    else if (i < na4 + nb4) { src = b; dst = ob; j = i - na4; }
    else if (i < na4 + nb4 + nc4) { src = c; dst = oc; j = i - na4 - nb4; }
    else return;
    float4 v = ((const float4*)src)[j];
    u32 w0 = (u32)f2bf(v.x) | ((u32)f2bf(v.y) << 16);
    u32 w1 = (u32)f2bf(v.z) | ((u32)f2bf(v.w) << 16);
    ((uint2*)dst)[j] = make_uint2(w0, w1);
}

// ---------------------------------------------------------------------------
// R6: proj GEMM re-tiled 64x64 for occupancy. Old 128x128 -> grid 192 WG on
// 256 CUs (25% CUs IDLE, rest 1 WG = zero TLP). New: 2x2 waves of 32x32,
// grid = 12 x 64 = 768 = exactly 3 WG/CU. LDS 16KB dbuf (2 gld_lds/wave/step,
// stage k+1 after barrier). B/A panels L2-resident re-reads.
// C[M,N] = A[M,K]*B[N,K]^T (+bias), bf16 in, fp32 out.
// ---------------------------------------------------------------------------
__global__ __launch_bounds__(256) void gemm_bt(const u16* __restrict__ A, const u16* __restrict__ Bm,
                                               float* __restrict__ C, const float* __restrict__ bias,
                                               int M, int N, int K) {
    __shared__ __align__(16) u16 sA[2][64 * 32];
    __shared__ __align__(16) u16 sB[2][64 * 32];
    const int t = threadIdx.x;
    const int wave = t >> 6, lane = t & 63;
    const int quad = lane >> 4, l16 = lane & 15;
    const int bm = blockIdx.y * 64, bn = blockIdx.x * 64;
    const int wr = wave >> 1, wc = wave & 1;

    f32x4 acc[2][2];
#pragma unroll
    for (int i = 0; i < 2; i++)
#pragma unroll
        for (int j = 0; j < 2; j++) acc[i][j] = f4zero();

    // stage 4KB A + 4KB B at k0 into buffer bi: wave w covers rows w*16..w*16+15
    auto stage = [&](int k0, int bi) {
        gld_lds16((char*)&sA[bi][0] + wave * 1024,
                  A + (size_t)(bm + wave * 16 + (lane >> 2)) * K + k0 + (lane & 3) * 8);
        gld_lds16((char*)&sB[bi][0] + wave * 1024,
                  Bm + (size_t)(bn + wave * 16 + (lane >> 2)) * K + k0 + (lane & 3) * 8);
    };

    stage(0, 0);
    int cur = 0;
    for (int k0 = 0; k0 < K; k0 += 32) {
        __syncthreads();  // drains DMA of buf[cur]; protects buf[cur^1] reuse
        if (k0 + 32 < K) stage(k0 + 32, cur ^ 1);
        const u16* pA = &sA[cur][0];
        const u16* pB = &sB[cur][0];
        bf16x8 af[2], bfr[2];
#pragma unroll
        for (int mb = 0; mb < 2; mb++)
            af[mb] = *(const bf16x8*)(pA + (wr * 32 + mb * 16 + l16) * 32 + quad * 8);
#pragma unroll
        for (int nb = 0; nb < 2; nb++)
            bfr[nb] = *(const bf16x8*)(pB + (wc * 32 + nb * 16 + l16) * 32 + quad * 8);
#pragma unroll
        for (int mb = 0; mb < 2; mb++)
#pragma unroll
            for (int nb = 0; nb < 2; nb++)
                acc[mb][nb] = __builtin_amdgcn_mfma_f32_16x16x32_bf16(af[mb], bfr[nb], acc[mb][nb], 0, 0, 0);
        cur ^= 1;
    }
#pragma unroll
    for (int mb = 0; mb < 2; mb++)
#pragma unroll
        for (int nb = 0; nb < 2; nb++) {
            int col = bn + wc * 32 + nb * 16 + l16;
            float bv = bias ? bias[col] : 0.f;
#pragma unroll
            for (int r = 0; r < 4; r++) {
                int row = bm + wr * 32 + mb * 16 + quad * 4 + r;
                C[(size_t)row * N + col] = acc[mb][nb][r] + bv;
            }
        }
}

// ---------------------------------------------------------------------------
// R6: QKV-GEMM (fused RoPE + flash-layout epilogue) re-tiled 128x64 with 4
// VERTICAL waves (each wave 32 rows x all 64 cols of one head window).
// grid = 36 x 32 = 1152 = 4.5 WG/CU (was 576 = 2.25, imbalanced 3-vs-2).
// Wave keeps the full head in-wave, so the R5-verified epilogue algebra
// carries over with:
//   rows: n = bm%NTOK + wave*32 + mb*16 + quad*4 + r   (mb 0..1)
//   cols: d = nb*16 + l16                              (nb 0..3)
//   RoPE pairs (d,d+32) = nb pairs {0,2},{1,3} in-thread (unchanged).
//   K frag-major: gm = wave*2+mb; tile_i = (bm%NTOK)/64 + (gm>>2); g = gm&3.
//   V: wave's 32 rows = ONE vT chunk = (bm%NTOK)/32 + wave;
//      jj=r for mb=0, jj=4+r for mb=1 -> one uint4 per nb at lane*8.
// LDS 24KB dbuf (A 8KB + B 4KB per buf): wave stages A-chunks {2w,2w+1},
// B-chunk {w} (1KB each, linear dest = chunk*1024 + lane*16).
// ---------------------------------------------------------------------------
__global__ __launch_bounds__(256) void gemm_qkv_rope(const u16* __restrict__ A, const u16* __restrict__ Bm,
                                                     const float* __restrict__ voxel,
                                                     const float* __restrict__ theta,
                                                     const int* __restrict__ gh_p, const int* __restrict__ gw_p,
                                                     u16* __restrict__ q_s, u16* __restrict__ k_s,
                                                     u16* __restrict__ vT, int M) {
    __shared__ __align__(16) u16 sA[2][128 * 32];
    __shared__ __align__(16) u16 sB[2][64 * 32];
    const int t = threadIdx.x;
    const int wave = t >> 6, lane = t & 63;
    const int quad = lane >> 4, l16 = lane & 15;
    const int bm = blockIdx.y * 128, bn = blockIdx.x * 64;
    const int K = DIM;

    f32x4 acc[2][4];
#pragma unroll
    for (int i = 0; i < 2; i++)
#pragma unroll
        for (int j = 0; j < 4; j++) acc[i][j] = f4zero();

    auto stage = [&](int k0, int bi) {
#pragma unroll
        for (int s = 0; s < 2; ++s) {
            int ci = wave * 2 + s;  // A chunk: rows ci*16..ci*16+15
            gld_lds16((char*)&sA[bi][0] + ci * 1024,
                      A + (size_t)(bm + ci * 16 + (lane >> 2)) * K + k0 + (lane & 3) * 8);
        }
        gld_lds16((char*)&sB[bi][0] + wave * 1024,
                  Bm + (size_t)(bn + wave * 16 + (lane >> 2)) * K + k0 + (lane & 3) * 8);
    };

    stage(0, 0);
    int cur = 0;
    for (int k0 = 0; k0 < K; k0 += 32) {
        __syncthreads();
        if (k0 + 32 < K) stage(k0 + 32, cur ^ 1);
        const u16* pA = &sA[cur][0];
        const u16* pB = &sB[cur][0];
        bf16x8 af[2], bfr[4];
#pragma unroll
        for (int mb = 0; mb < 2; mb++)
            af[mb] = *(const bf16x8*)(pA + (wave * 32 + mb * 16 + l16) * 32 + quad * 8);
#pragma unroll
        for (int nb = 0; nb < 4; nb++)
            bfr[nb] = *(const bf16x8*)(pB + (nb * 16 + l16) * 32 + quad * 8);
#pragma unroll
        for (int mb = 0; mb < 2; mb++)
#pragma unroll
            for (int nb = 0; nb < 4; nb++)
                acc[mb][nb] = __builtin_amdgcn_mfma_f32_16x16x32_bf16(af[mb], bfr[nb], acc[mb][nb], 0, 0, 0);
        cur ^= 1;
    }

    // ---------------- fused epilogue ----------------
    const int col0 = bn;                     // 64-col block = one head window
    const int typ = col0 / DIM;              // 0=Q, 1=K, 2=V (block-uniform)
    const int h = (col0 % DIM) >> 6;
    const int b = bm / NTOK;
    const int n0 = (bm % NTOK) + wave * 32;  // wave's token base (mult of 32)
    const size_t bh = (size_t)b * NHEADS + h;

    if (typ == 2) {
        // ---- V: register-local fragment-major pack (one chunk per wave) ----
        int chunk = ((bm % NTOK) >> 5) + wave;
        u16* base = vT + ((size_t)bh * 64 + chunk) * 2048;
#pragma unroll
        for (int nb = 0; nb < 4; nb++) {
            u32 w0 = (u32)f2bf(acc[0][nb][0]) | ((u32)f2bf(acc[0][nb][1]) << 16);
            u32 w1 = (u32)f2bf(acc[0][nb][2]) | ((u32)f2bf(acc[0][nb][3]) << 16);
            u32 w2 = (u32)f2bf(acc[1][nb][0]) | ((u32)f2bf(acc[1][nb][1]) << 16);
            u32 w3 = (u32)f2bf(acc[1][nb][2]) | ((u32)f2bf(acc[1][nb][3]) << 16);
            *(uint4*)(base + nb * 512 + lane * 8) = make_uint4(w0, w1, w2, w3);
        }
    } else {
        // ---- Q/K: in-register RoPE ----
        const int gh = *gh_p, gw = *gw_p;
        const float qsc = (typ == 0) ? 0.125f * LOG2E : 1.0f;
        const float th0 = theta[h * DHALF + l16];
        const float th1 = theta[h * DHALF + 16 + l16];
        const int ax0 = l16 % 3, ax1 = (16 + l16) % 3;
        const float vx0 = voxel[ax0], vx1 = voxel[ax1];
#pragma unroll
        for (int mb = 0; mb < 2; mb++)
#pragma unroll
            for (int r = 0; r < 4; r++) {
                int n = n0 + mb * 16 + quad * 4 + r;
                int xw = n % gw;
                int rem = n / gw;
                int yh = rem % gh;
                int zd = rem / gh;
                float c0 = (float)(ax0 == 0 ? zd : (ax0 == 1 ? yh : xw)) * vx0;
                float c1 = (float)(ax1 == 0 ? zd : (ax1 == 1 ? yh : xw)) * vx1;
                float s0, co0, s1, co1;
                __sincosf(c0 * th0, &s0, &co0);
                __sincosf(c1 * th1, &s1, &co1);
                float t1a = acc[mb][0][r], t2a = acc[mb][2][r];
                float o1a = (t1a * co0 - t2a * s0) * qsc, o2a = (t1a * s0 + t2a * co0) * qsc;
                float t1b = acc[mb][1][r], t2b = acc[mb][3][r];
                float o1b = (t1b * co1 - t2b * s1) * qsc, o2b = (t1b * s1 + t2b * co1) * qsc;
                if (typ == 0) {
                    u16* dq = q_s + (bh * NTOK + n) * HDIM;
                    dq[l16] = f2bf(o1a);
                    dq[l16 + DHALF] = f2bf(o2a);
                    dq[16 + l16] = f2bf(o1b);
                    dq[48 + l16] = f2bf(o2b);
                } else {
                    // fragment-major K (matches flash's kf read pattern)
                    int gm = wave * 2 + mb;
                    int tile_i = ((bm % NTOK) >> 6) + (gm >> 2);
                    int g = gm & 3;
                    int k16 = quad * 4 + r;
                    size_t baseo = bh * (size_t)NTOK * HDIM + (size_t)tile_i * 4096 + g * 1024;
                    int j = l16 & 7;
                    size_t oa = baseo + (size_t)(((l16 >> 3) * 16 + k16) * 8 + j);
                    size_t ob = baseo + (size_t)((((2 + (l16 >> 3)) * 16) + k16) * 8 + j);
                    k_s[oa] = f2bf(o1a);
                    k_s[oa + 512] = f2bf(o2a);
                    k_s[ob] = f2bf(o1b);
                    k_s[ob + 512] = f2bf(o2b);
                }
            }
    }
}

// ---------------------------------------------------------------------------
// Flash attention v10 (measured-best: 52.2-54.5us, UNCHANGED):
// 4 waves x 16 q-rows = 64 rows/WG; grid = 768 = EXACTLY 3 WG/CU, 12
// waves/CU. Fragment-major K/V: every ds_read_b128 at base+lane*16 -> zero
// bank conflicts. All-register P path (S^T = K*Q^T; exp2; feed PV as
// A-frag), ones-column row-sum MFMA, fixed-base softmax.
// ---------------------------------------------------------------------------
__global__ __launch_bounds__(256) void flash_attn(const u16* __restrict__ Q, const u16* __restrict__ Kp,
                                                  const u16* __restrict__ Vp, u16* __restrict__ Out, int NBH) {
    int i = blockIdx.x;
    int bh_i = i % NBH;   // all of a bh's WGs land on XCD bh%8 (24%8==0)
    int qt = i / NBH;     // 0..31
    int b = bh_i / NHEADS, h = bh_i % NHEADS;
    int t = threadIdx.x, wave = t >> 6, lane = t & 63, quad = lane >> 4, l16 = lane & 15;
    size_t bh = (size_t)b * NHEADS + h;
    const u16* Qb = Q + bh * NTOK * HDIM;
    const u16* Kb = Kp + bh * NTOK * HDIM;  // frag-major 4096-elem tiles
    const u16* Vb = Vp + bh * NTOK * HDIM;  // frag-major: 2 chunks x 2048 per tile

    __shared__ __align__(16) u16 smem[2][8192];  // [buf][K 4096 | V 4096] = 32KB

    const int q0 = qt * 64 + wave * 16;  // 16 q-rows per wave
    bf16x8 qf[2];
#pragma unroll
    for (int kc = 0; kc < 2; kc++)
        qf[kc] = *(const bf16x8*)(Qb + (size_t)(q0 + l16) * HDIM + kc * 32 + quad * 8);

    // ones B-frag: col 0 accumulates the P row-sum
    s16x8 ov;
#pragma unroll
    for (int j = 0; j < 8; j++) ov[j] = (l16 == 0) ? (short)0x3F80 : (short)0;

    f32x4 o[5];
#pragma unroll
    for (int db = 0; db < 5; db++) o[db] = f4zero();

    // stage 8KB K + 8KB V of tile kt into buffer bi (4 x 1KB DMA per wave)
    auto stage = [&](int kt, int bi) {
        const u16* Kg = Kb + (size_t)kt * 4096;
        const u16* Vg = Vb + (size_t)kt * 4096;
        u16* buf = &smem[bi][0];
#pragma unroll
        for (int s = 0; s < 2; s++) {
            gld_lds16(buf + (wave * 2 + s) * 512, Kg + (wave * 2 + s) * 512 + lane * 8);
            gld_lds16(buf + 4096 + (wave * 2 + s) * 512, Vg + (wave * 2 + s) * 512 + lane * 8);
        }
    };

    stage(0, 0);
    int cur = 0;
    for (int kt = 0; kt < NTOK / 64; ++kt) {
        __syncthreads();  // drains DMA of buf[cur]; protects buf[cur^1] reuse
        if (kt + 1 < NTOK / 64) stage(kt + 1, cur ^ 1);
        const u16* sK = &smem[cur][0];
        const u16* sV = &smem[cur][4096];
#pragma unroll
        for (int c = 0; c < 2; ++c) {
            bf16x8 kf[2][2];
#pragma unroll
            for (int kb2 = 0; kb2 < 2; kb2++)
#pragma unroll
                for (int kc = 0; kc < 2; kc++)
                    kf[kb2][kc] = *(const bf16x8*)(sK + ((c * 2 + kb2) * 2 + kc) * 512 + lane * 8);
            s16x8 bv[4];
#pragma unroll
            for (int db = 0; db < 4; db++)
                bv[db] = *(const s16x8*)(sV + c * 2048 + db * 512 + lane * 8);
            f32x4 st0, st1;
            {
                f32x4 z = f4zero();
                z = __builtin_amdgcn_mfma_f32_16x16x32_bf16(kf[0][0], qf[0], z, 0, 0, 0);
                st0 = __builtin_amdgcn_mfma_f32_16x16x32_bf16(kf[0][1], qf[1], z, 0, 0, 0);
                f32x4 z2 = f4zero();
                z2 = __builtin_amdgcn_mfma_f32_16x16x32_bf16(kf[1][0], qf[0], z2, 0, 0, 0);
                st1 = __builtin_amdgcn_mfma_f32_16x16x32_bf16(kf[1][1], qf[1], z2, 0, 0, 0);
            }
            bf16x8 pb;
#pragma unroll
            for (int r = 0; r < 4; r++) {
                pb[r] = (__bf16)__builtin_exp2f(st0[r]);
                pb[r + 4] = (__bf16)__builtin_exp2f(st1[r]);
            }
#pragma unroll
            for (int db = 0; db < 4; db++)
                o[db] = __builtin_amdgcn_mfma_f32_16x16x32_bf16(pb, __builtin_bit_cast(bf16x8, bv[db]),
                                                                o[db], 0, 0, 0);
            o[4] = __builtin_amdgcn_mfma_f32_16x16x32_bf16(pb, __builtin_bit_cast(bf16x8, ov),
                                                           o[4], 0, 0, 0);
        }
        cur ^= 1;
    }

    // epilogue: broadcast row-sum from col-0 lanes, normalize, store bf16
#pragma unroll
    for (int r = 0; r < 4; r++) {
        float s = __shfl(o[4][r], lane & 48);  // lane quad*16 holds the sum
        float inv = 1.0f / s;
        int n = q0 + quad * 4 + r;
        u16* dst = Out + ((size_t)b * NTOK + n) * DIM + h * HDIM + l16;
#pragma unroll
        for (int db = 0; db < 4; db++)
            dst[db * 16] = f2bf(o[db][r] * inv);
    }
}

// ---------------------------------------------------------------------------
extern "C" void kernel_launch(void* const* d_in, const int* in_sizes, int n_in,
                              void* d_out, int out_size, void* d_ws, size_t ws_size,
                              hipStream_t stream) {
    const float* x = (const float*)d_in[0];
    const float* voxel = (const float*)d_in[1];
    const float* w_qkv = (const float*)d_in[2];
    const float* w_proj = (const float*)d_in[3];
    const float* b_proj = (const float*)d_in[4];
    const float* theta = (const float*)d_in[5];
    const int* gh_p = (const int*)d_in[7];
    const int* gw_p = (const int*)d_in[8];
    const int B = in_sizes[0] / (NTOK * DIM);
    const int M = B * NTOK;

    char* p = (char*)d_ws;
    u16* xb = (u16*)p;       p += (size_t)M * DIM * 2;
    u16* wqkvb = (u16*)p;    p += (size_t)3 * DIM * DIM * 2;
    u16* wprojb = (u16*)p;   p += (size_t)DIM * DIM * 2;
    u16* q_s = (u16*)p;      p += (size_t)M * DIM * 2;
    u16* k_s = (u16*)p;      p += (size_t)M * DIM * 2;
    u16* vT = (u16*)p;       p += (size_t)M * DIM * 2;
    u16* attn = (u16*)p;     p += (size_t)M * DIM * 2;

    int na4 = M * DIM / 4, nb4 = 3 * DIM * DIM / 4, nc4 = DIM * DIM / 4;
    cast3_f32_to_bf16<<<dim3((na4 + nb4 + nc4 + 255) / 256), 256, 0, stream>>>(
        x, xb, na4, w_qkv, wqkvb, nb4, w_proj, wprojb, nc4);

    // QKV GEMM with fused RoPE + flash-layout epilogue: 128x64 tiles, 1152 WG
    gemm_qkv_rope<<<dim3(QKVN / 64, M / 128), 256, 0, stream>>>(
        xb, wqkvb, voxel, theta, gh_p, gw_p, q_s, k_s, vT, M);

    flash_attn<<<dim3((B * NHEADS * NTOK) / 64), 256, 0, stream>>>(q_s, k_s, vT, attn, B * NHEADS);

    // proj GEMM: 64x64 tiles -> 768 WG = 3 WG/CU (was 192 WG, 25% CUs idle)
    gemm_bt<<<dim3(DIM / 64, M / 64), 256, 0, stream>>>(attn, wprojb, (float*)d_out, b_proj, M, DIM, DIM);
}

// Round 7
// 175.150 us; speedup vs baseline: 1.9406x; 1.0083x over previous
//
#include <hip/hip_runtime.h>
#include <stdint.h>

#define DIM 768
#define NHEADS 12
#define HDIM 64
#define DHALF 32
#define NTOK 2048
#define QKVN 2304
#define LOG2E 1.44269504088896340736f

typedef unsigned short u16;
typedef unsigned int u32;
typedef __bf16 bf16x8 __attribute__((ext_vector_type(8)));
typedef short s16x8 __attribute__((ext_vector_type(8)));
typedef float f32x4 __attribute__((ext_vector_type(4)));

__device__ __forceinline__ f32x4 f4zero() { f32x4 z = {0.f, 0.f, 0.f, 0.f}; return z; }

// fp32 -> bf16 bits, round-to-nearest-even
__device__ __forceinline__ u16 f2bf(float f) {
    u32 u = __builtin_bit_cast(u32, f);
    u32 r = (u + 0x7FFFu + ((u >> 16) & 1u)) >> 16;
    return (u16)r;
}

// async global->LDS, 16B per lane. LDS dest = wave-uniform base + lane*16.
__device__ __forceinline__ void gld_lds16(void* lds, const void* g) {
    __builtin_amdgcn_global_load_lds((const __attribute__((address_space(1))) u32*)g,
                                     (__attribute__((address_space(3))) u32*)lds,
                                     16, 0, 0);
}

// ---------------------------------------------------------------------------
// fused fp32 -> bf16 cast of x, w_qkv, w_proj (one launch)
// ---------------------------------------------------------------------------
__global__ __launch_bounds__(256) void cast3_f32_to_bf16(const float* __restrict__ a, u16* __restrict__ oa, int na4,
                                                         const float* __restrict__ b, u16* __restrict__ ob, int nb4,
                                                         const float* __restrict__ c, u16* __restrict__ oc, int nc4) {
    int i = blockIdx.x * 256 + threadIdx.x;
    const float* src;
    u16* dst;
    int j = i;
    if (i < na4) { src = a; dst = oa; }
    else if (i < na4 + nb4) { src = b; dst = ob; j = i - na4; }
    else if (i < na4 + nb4 + nc4) { src = c; dst = oc; j = i - na4 - nb4; }
    else return;
    float4 v = ((const float4*)src)[j];
    u32 w0 = (u32)f2bf(v.x) | ((u32)f2bf(v.y) << 16);
    u32 w1 = (u32)f2bf(v.z) | ((u32)f2bf(v.w) << 16);
    ((uint2*)dst)[j] = make_uint2(w0, w1);
}

// ---------------------------------------------------------------------------
// proj GEMM 64x64 tiles (R6 shape: 768 WG = 3 WG/CU balanced), dbuf gld_lds.
// C[M,N] = A[M,K]*B[N,K]^T (+bias), bf16 in, fp32 out.
// ---------------------------------------------------------------------------
__global__ __launch_bounds__(256) void gemm_bt(const u16* __restrict__ A, const u16* __restrict__ Bm,
                                               float* __restrict__ C, const float* __restrict__ bias,
                                               int M, int N, int K) {
    __shared__ __align__(16) u16 sA[2][64 * 32];
    __shared__ __align__(16) u16 sB[2][64 * 32];
    const int t = threadIdx.x;
    const int wave = t >> 6, lane = t & 63;
    const int quad = lane >> 4, l16 = lane & 15;
    const int bm = blockIdx.y * 64, bn = blockIdx.x * 64;
    const int wr = wave >> 1, wc = wave & 1;

    f32x4 acc[2][2];
#pragma unroll
    for (int i = 0; i < 2; i++)
#pragma unroll
        for (int j = 0; j < 2; j++) acc[i][j] = f4zero();

    auto stage = [&](int k0, int bi) {
        gld_lds16((char*)&sA[bi][0] + wave * 1024,
                  A + (size_t)(bm + wave * 16 + (lane >> 2)) * K + k0 + (lane & 3) * 8);
        gld_lds16((char*)&sB[bi][0] + wave * 1024,
                  Bm + (size_t)(bn + wave * 16 + (lane >> 2)) * K + k0 + (lane & 3) * 8);
    };

    stage(0, 0);
    int cur = 0;
    for (int k0 = 0; k0 < K; k0 += 32) {
        __syncthreads();  // drains DMA of buf[cur]; protects buf[cur^1] reuse
        if (k0 + 32 < K) stage(k0 + 32, cur ^ 1);
        const u16* pA = &sA[cur][0];
        const u16* pB = &sB[cur][0];
        bf16x8 af[2], bfr[2];
#pragma unroll
        for (int mb = 0; mb < 2; mb++)
            af[mb] = *(const bf16x8*)(pA + (wr * 32 + mb * 16 + l16) * 32 + quad * 8);
#pragma unroll
        for (int nb = 0; nb < 2; nb++)
            bfr[nb] = *(const bf16x8*)(pB + (wc * 32 + nb * 16 + l16) * 32 + quad * 8);
#pragma unroll
        for (int mb = 0; mb < 2; mb++)
#pragma unroll
            for (int nb = 0; nb < 2; nb++)
                acc[mb][nb] = __builtin_amdgcn_mfma_f32_16x16x32_bf16(af[mb], bfr[nb], acc[mb][nb], 0, 0, 0);
        cur ^= 1;
    }
#pragma unroll
    for (int mb = 0; mb < 2; mb++)
#pragma unroll
        for (int nb = 0; nb < 2; nb++) {
            int col = bn + wc * 32 + nb * 16 + l16;
            float bv = bias ? bias[col] : 0.f;
#pragma unroll
            for (int r = 0; r < 4; r++) {
                int row = bm + wr * 32 + mb * 16 + quad * 4 + r;
                C[(size_t)row * N + col] = acc[mb][nb][r] + bv;
            }
        }
}

// ---------------------------------------------------------------------------
// QKV-GEMM (fused RoPE + flash-layout epilogue), 128x64 tiles, 4 vertical
// waves, grid 1152 = 4.5 WG/CU (R6 shape).
// R7 change: POW2 FAST PATH for the n -> (zd,yh,xw) decomposition. The
// epilogue ran 8 runtime integer divisions per thread (~240 VALU ops via
// v_rcp sequences) -- at 12 Q/K waves/CU that is ~5 us chip-wide. Grid is
// 8x16x16 so gh,gw are pow2: shift/mask path (~3 ops), generic div path
// branched around (uniform cond -> s_cbranch skip).
// ---------------------------------------------------------------------------
__global__ __launch_bounds__(256) void gemm_qkv_rope(const u16* __restrict__ A, const u16* __restrict__ Bm,
                                                     const float* __restrict__ voxel,
                                                     const float* __restrict__ theta,
                                                     const int* __restrict__ gh_p, const int* __restrict__ gw_p,
                                                     u16* __restrict__ q_s, u16* __restrict__ k_s,
                                                     u16* __restrict__ vT, int M) {
    __shared__ __align__(16) u16 sA[2][128 * 32];
    __shared__ __align__(16) u16 sB[2][64 * 32];
    const int t = threadIdx.x;
    const int wave = t >> 6, lane = t & 63;
    const int quad = lane >> 4, l16 = lane & 15;
    const int bm = blockIdx.y * 128, bn = blockIdx.x * 64;
    const int K = DIM;

    f32x4 acc[2][4];
#pragma unroll
    for (int i = 0; i < 2; i++)
#pragma unroll
        for (int j = 0; j < 4; j++) acc[i][j] = f4zero();

    auto stage = [&](int k0, int bi) {
#pragma unroll
        for (int s = 0; s < 2; ++s) {
            int ci = wave * 2 + s;  // A chunk: rows ci*16..ci*16+15
            gld_lds16((char*)&sA[bi][0] + ci * 1024,
                      A + (size_t)(bm + ci * 16 + (lane >> 2)) * K + k0 + (lane & 3) * 8);
        }
        gld_lds16((char*)&sB[bi][0] + wave * 1024,
                  Bm + (size_t)(bn + wave * 16 + (lane >> 2)) * K + k0 + (lane & 3) * 8);
    };

    stage(0, 0);
    int cur = 0;
    for (int k0 = 0; k0 < K; k0 += 32) {
        __syncthreads();
        if (k0 + 32 < K) stage(k0 + 32, cur ^ 1);
        const u16* pA = &sA[cur][0];
        const u16* pB = &sB[cur][0];
        bf16x8 af[2], bfr[4];
#pragma unroll
        for (int mb = 0; mb < 2; mb++)
            af[mb] = *(const bf16x8*)(pA + (wave * 32 + mb * 16 + l16) * 32 + quad * 8);
#pragma unroll
        for (int nb = 0; nb < 4; nb++)
            bfr[nb] = *(const bf16x8*)(pB + (nb * 16 + l16) * 32 + quad * 8);
#pragma unroll
        for (int mb = 0; mb < 2; mb++)
#pragma unroll
            for (int nb = 0; nb < 4; nb++)
                acc[mb][nb] = __builtin_amdgcn_mfma_f32_16x16x32_bf16(af[mb], bfr[nb], acc[mb][nb], 0, 0, 0);
        cur ^= 1;
    }

    // ---------------- fused epilogue ----------------
    const int col0 = bn;                     // 64-col block = one head window
    const int typ = col0 / DIM;              // 0=Q, 1=K, 2=V (block-uniform)
    const int h = (col0 % DIM) >> 6;
    const int b = bm / NTOK;
    const int n0 = (bm % NTOK) + wave * 32;  // wave's token base (mult of 32)
    const size_t bh = (size_t)b * NHEADS + h;

    if (typ == 2) {
        // ---- V: register-local fragment-major pack (one chunk per wave) ----
        int chunk = ((bm % NTOK) >> 5) + wave;
        u16* base = vT + ((size_t)bh * 64 + chunk) * 2048;
#pragma unroll
        for (int nb = 0; nb < 4; nb++) {
            u32 w0 = (u32)f2bf(acc[0][nb][0]) | ((u32)f2bf(acc[0][nb][1]) << 16);
            u32 w1 = (u32)f2bf(acc[0][nb][2]) | ((u32)f2bf(acc[0][nb][3]) << 16);
            u32 w2 = (u32)f2bf(acc[1][nb][0]) | ((u32)f2bf(acc[1][nb][1]) << 16);
            u32 w3 = (u32)f2bf(acc[1][nb][2]) | ((u32)f2bf(acc[1][nb][3]) << 16);
            *(uint4*)(base + nb * 512 + lane * 8) = make_uint4(w0, w1, w2, w3);
        }
    } else {
        // ---- Q/K: in-register RoPE ----
        const int gh = *gh_p, gw = *gw_p;
        const bool p2 = ((gw & (gw - 1)) == 0) && ((gh & (gh - 1)) == 0);
        const int wsh = 31 - __builtin_clz(gw), hsh = 31 - __builtin_clz(gh);
        const float qsc = (typ == 0) ? 0.125f * LOG2E : 1.0f;
        const float th0 = theta[h * DHALF + l16];
        const float th1 = theta[h * DHALF + 16 + l16];
        const int ax0 = l16 % 3, ax1 = (16 + l16) % 3;
        const float vx0 = voxel[ax0], vx1 = voxel[ax1];
#pragma unroll
        for (int mb = 0; mb < 2; mb++)
#pragma unroll
            for (int r = 0; r < 4; r++) {
                int n = n0 + mb * 16 + quad * 4 + r;
                int xw, yh, zd;
                if (p2) {  // pow2 grid (the actual case: 8x16x16): 3 ops
                    xw = n & (gw - 1);
                    int rem = n >> wsh;
                    yh = rem & (gh - 1);
                    zd = rem >> hsh;
                } else {   // generic path, branched around at runtime
                    xw = n % gw;
                    int rem = n / gw;
                    yh = rem % gh;
                    zd = rem / gh;
                }
                float c0 = (float)(ax0 == 0 ? zd : (ax0 == 1 ? yh : xw)) * vx0;
                float c1 = (float)(ax1 == 0 ? zd : (ax1 == 1 ? yh : xw)) * vx1;
                float s0, co0, s1, co1;
                __sincosf(c0 * th0, &s0, &co0);
                __sincosf(c1 * th1, &s1, &co1);
                float t1a = acc[mb][0][r], t2a = acc[mb][2][r];
                float o1a = (t1a * co0 - t2a * s0) * qsc, o2a = (t1a * s0 + t2a * co0) * qsc;
                float t1b = acc[mb][1][r], t2b = acc[mb][3][r];
                float o1b = (t1b * co1 - t2b * s1) * qsc, o2b = (t1b * s1 + t2b * co1) * qsc;
                if (typ == 0) {
                    u16* dq = q_s + (bh * NTOK + n) * HDIM;
                    dq[l16] = f2bf(o1a);
                    dq[l16 + DHALF] = f2bf(o2a);
                    dq[16 + l16] = f2bf(o1b);
                    dq[48 + l16] = f2bf(o2b);
                } else {
                    // fragment-major K (matches flash's kf read pattern)
                    int gm = wave * 2 + mb;
                    int tile_i = ((bm % NTOK) >> 6) + (gm >> 2);
                    int g = gm & 3;
                    int k16 = quad * 4 + r;
                    size_t baseo = bh * (size_t)NTOK * HDIM + (size_t)tile_i * 4096 + g * 1024;
                    int j = l16 & 7;
                    size_t oa = baseo + (size_t)(((l16 >> 3) * 16 + k16) * 8 + j);
                    size_t ob = baseo + (size_t)((((2 + (l16 >> 3)) * 16) + k16) * 8 + j);
                    k_s[oa] = f2bf(o1a);
                    k_s[oa + 512] = f2bf(o2a);
                    k_s[ob] = f2bf(o1b);
                    k_s[ob + 512] = f2bf(o2b);
                }
            }
    }
}

// ---------------------------------------------------------------------------
// Flash attention v10 + s_setprio (R7): structure identical to the measured
// 53.6us kernel (4 waves x 16 q-rows, grid 768 = 3 WG/CU, frag-major K/V,
// zero bank conflicts, dbuf gld_lds staging, fixed-base softmax).
// R7 adds ONLY setprio(1) around the S-MFMA and PV-MFMA clusters (m191:
// +4-7% on latency-bound multi-WG attn; R3 never tested it cleanly --
// its regression was attributed to the device fence via FETCH +67%).
// ---------------------------------------------------------------------------
__global__ __launch_bounds__(256) void flash_attn(const u16* __restrict__ Q, const u16* __restrict__ Kp,
                                                  const u16* __restrict__ Vp, u16* __restrict__ Out, int NBH) {
    int i = blockIdx.x;
    int bh_i = i % NBH;   // all of a bh's WGs land on XCD bh%8 (24%8==0)
    int qt = i / NBH;     // 0..31
    int b = bh_i / NHEADS, h = bh_i % NHEADS;
    int t = threadIdx.x, wave = t >> 6, lane = t & 63, quad = lane >> 4, l16 = lane & 15;
    size_t bh = (size_t)b * NHEADS + h;
    const u16* Qb = Q + bh * NTOK * HDIM;
    const u16* Kb = Kp + bh * NTOK * HDIM;  // frag-major 4096-elem tiles
    const u16* Vb = Vp + bh * NTOK * HDIM;  // frag-major: 2 chunks x 2048 per tile

    __shared__ __align__(16) u16 smem[2][8192];  // [buf][K 4096 | V 4096] = 32KB

    const int q0 = qt * 64 + wave * 16;  // 16 q-rows per wave
    bf16x8 qf[2];
#pragma unroll
    for (int kc = 0; kc < 2; kc++)
        qf[kc] = *(const bf16x8*)(Qb + (size_t)(q0 + l16) * HDIM + kc * 32 + quad * 8);

    // ones B-frag: col 0 accumulates the P row-sum
    s16x8 ov;
#pragma unroll
    for (int j = 0; j < 8; j++) ov[j] = (l16 == 0) ? (short)0x3F80 : (short)0;

    f32x4 o[5];
#pragma unroll
    for (int db = 0; db < 5; db++) o[db] = f4zero();

    // stage 8KB K + 8KB V of tile kt into buffer bi (4 x 1KB DMA per wave)
    auto stage = [&](int kt, int bi) {
        const u16* Kg = Kb + (size_t)kt * 4096;
        const u16* Vg = Vb + (size_t)kt * 4096;
        u16* buf = &smem[bi][0];
#pragma unroll
        for (int s = 0; s < 2; s++) {
            gld_lds16(buf + (wave * 2 + s) * 512, Kg + (wave * 2 + s) * 512 + lane * 8);
            gld_lds16(buf + 4096 + (wave * 2 + s) * 512, Vg + (wave * 2 + s) * 512 + lane * 8);
        }
    };

    stage(0, 0);
    int cur = 0;
    for (int kt = 0; kt < NTOK / 64; ++kt) {
        __syncthreads();  // drains DMA of buf[cur]; protects buf[cur^1] reuse
        if (kt + 1 < NTOK / 64) stage(kt + 1, cur ^ 1);
        const u16* sK = &smem[cur][0];
        const u16* sV = &smem[cur][4096];
#pragma unroll
        for (int c = 0; c < 2; ++c) {
            bf16x8 kf[2][2];
#pragma unroll
            for (int kb2 = 0; kb2 < 2; kb2++)
#pragma unroll
                for (int kc = 0; kc < 2; kc++)
                    kf[kb2][kc] = *(const bf16x8*)(sK + ((c * 2 + kb2) * 2 + kc) * 512 + lane * 8);
            s16x8 bv[4];
#pragma unroll
            for (int db = 0; db < 4; db++)
                bv[db] = *(const s16x8*)(sV + c * 2048 + db * 512 + lane * 8);
            f32x4 st0, st1;
            __builtin_amdgcn_s_setprio(1);
            {
                f32x4 z = f4zero();
                z = __builtin_amdgcn_mfma_f32_16x16x32_bf16(kf[0][0], qf[0], z, 0, 0, 0);
                st0 = __builtin_amdgcn_mfma_f32_16x16x32_bf16(kf[0][1], qf[1], z, 0, 0, 0);
                f32x4 z2 = f4zero();
                z2 = __builtin_amdgcn_mfma_f32_16x16x32_bf16(kf[1][0], qf[0], z2, 0, 0, 0);
                st1 = __builtin_amdgcn_mfma_f32_16x16x32_bf16(kf[1][1], qf[1], z2, 0, 0, 0);
            }
            __builtin_amdgcn_s_setprio(0);
            bf16x8 pb;
#pragma unroll
            for (int r = 0; r < 4; r++) {
                pb[r] = (__bf16)__builtin_exp2f(st0[r]);
                pb[r + 4] = (__bf16)__builtin_exp2f(st1[r]);
            }
            __builtin_amdgcn_s_setprio(1);
#pragma unroll
            for (int db = 0; db < 4; db++)
                o[db] = __builtin_amdgcn_mfma_f32_16x16x32_bf16(pb, __builtin_bit_cast(bf16x8, bv[db]),
                                                                o[db], 0, 0, 0);
            o[4] = __builtin_amdgcn_mfma_f32_16x16x32_bf16(pb, __builtin_bit_cast(bf16x8, ov),
                                                           o[4], 0, 0, 0);
            __builtin_amdgcn_s_setprio(0);
        }
        cur ^= 1;
    }

    // epilogue: broadcast row-sum from col-0 lanes, normalize, store bf16
#pragma unroll
    for (int r = 0; r < 4; r++) {
        float s = __shfl(o[4][r], lane & 48);  // lane quad*16 holds the sum
        float inv = 1.0f / s;
        int n = q0 + quad * 4 + r;
        u16* dst = Out + ((size_t)b * NTOK + n) * DIM + h * HDIM + l16;
#pragma unroll
        for (int db = 0; db < 4; db++)
            dst[db * 16] = f2bf(o[db][r] * inv);
    }
}

// ---------------------------------------------------------------------------
extern "C" void kernel_launch(void* const* d_in, const int* in_sizes, int n_in,
                              void* d_out, int out_size, void* d_ws, size_t ws_size,
                              hipStream_t stream) {
    const float* x = (const float*)d_in[0];
    const float* voxel = (const float*)d_in[1];
    const float* w_qkv = (const float*)d_in[2];
    const float* w_proj = (const float*)d_in[3];
    const float* b_proj = (const float*)d_in[4];
    const float* theta = (const float*)d_in[5];
    const int* gh_p = (const int*)d_in[7];
    const int* gw_p = (const int*)d_in[8];
    const int B = in_sizes[0] / (NTOK * DIM);
    const int M = B * NTOK;

    char* p = (char*)d_ws;
    u16* xb = (u16*)p;       p += (size_t)M * DIM * 2;
    u16* wqkvb = (u16*)p;    p += (size_t)3 * DIM * DIM * 2;
    u16* wprojb = (u16*)p;   p += (size_t)DIM * DIM * 2;
    u16* q_s = (u16*)p;      p += (size_t)M * DIM * 2;
    u16* k_s = (u16*)p;      p += (size_t)M * DIM * 2;
    u16* vT = (u16*)p;       p += (size_t)M * DIM * 2;
    u16* attn = (u16*)p;     p += (size_t)M * DIM * 2;

    int na4 = M * DIM / 4, nb4 = 3 * DIM * DIM / 4, nc4 = DIM * DIM / 4;
    cast3_f32_to_bf16<<<dim3((na4 + nb4 + nc4 + 255) / 256), 256, 0, stream>>>(
        x, xb, na4, w_qkv, wqkvb, nb4, w_proj, wprojb, nc4);

    // QKV GEMM with fused RoPE + flash-layout epilogue: 128x64 tiles, 1152 WG
    gemm_qkv_rope<<<dim3(QKVN / 64, M / 128), 256, 0, stream>>>(
        xb, wqkvb, voxel, theta, gh_p, gw_p, q_s, k_s, vT, M);

    flash_attn<<<dim3((B * NHEADS * NTOK) / 64), 256, 0, stream>>>(q_s, k_s, vT, attn, B * NHEADS);

    // proj GEMM: 64x64 tiles -> 768 WG = 3 WG/CU
    gemm_bt<<<dim3(DIM / 64, M / 64), 256, 0, stream>>>(attn, wprojb, (float*)d_out, b_proj, M, DIM, DIM);
}

// Round 8
// 174.748 us; speedup vs baseline: 1.9450x; 1.0023x over previous
//
#include <hip/hip_runtime.h>
#include <stdint.h>

#define DIM 768
#define NHEADS 12
#define HDIM 64
#define DHALF 32
#define NTOK 2048
#define QKVN 2304
#define LOG2E 1.44269504088896340736f

typedef unsigned short u16;
typedef unsigned int u32;
typedef __bf16 bf16x8 __attribute__((ext_vector_type(8)));
typedef short s16x8 __attribute__((ext_vector_type(8)));
typedef float f32x4 __attribute__((ext_vector_type(4)));

__device__ __forceinline__ f32x4 f4zero() { f32x4 z = {0.f, 0.f, 0.f, 0.f}; return z; }

// fp32 -> bf16 bits, round-to-nearest-even
__device__ __forceinline__ u16 f2bf(float f) {
    u32 u = __builtin_bit_cast(u32, f);
    u32 r = (u + 0x7FFFu + ((u >> 16) & 1u)) >> 16;
    return (u16)r;
}

// async global->LDS, 16B per lane. LDS dest = wave-uniform base + lane*16.
__device__ __forceinline__ void gld_lds16(void* lds, const void* g) {
    __builtin_amdgcn_global_load_lds((const __attribute__((address_space(1))) u32*)g,
                                     (__attribute__((address_space(3))) u32*)lds,
                                     16, 0, 0);
}

// ---------------------------------------------------------------------------
// fused fp32 -> bf16 cast of x, w_qkv, w_proj (one launch)
// ---------------------------------------------------------------------------
__global__ __launch_bounds__(256) void cast3_f32_to_bf16(const float* __restrict__ a, u16* __restrict__ oa, int na4,
                                                         const float* __restrict__ b, u16* __restrict__ ob, int nb4,
                                                         const float* __restrict__ c, u16* __restrict__ oc, int nc4) {
    int i = blockIdx.x * 256 + threadIdx.x;
    const float* src;
    u16* dst;
    int j = i;
    if (i < na4) { src = a; dst = oa; }
    else if (i < na4 + nb4) { src = b; dst = ob; j = i - na4; }
    else if (i < na4 + nb4 + nc4) { src = c; dst = oc; j = i - na4 - nb4; }
    else return;
    float4 v = ((const float4*)src)[j];
    u32 w0 = (u32)f2bf(v.x) | ((u32)f2bf(v.y) << 16);
    u32 w1 = (u32)f2bf(v.z) | ((u32)f2bf(v.w) << 16);
    ((uint2*)dst)[j] = make_uint2(w0, w1);
}

// ---------------------------------------------------------------------------
// proj GEMM 64x64 tiles (768 WG = 3 WG/CU balanced), dbuf gld_lds.
// C[M,N] = A[M,K]*B[N,K]^T (+bias), bf16 in, fp32 out.
// ---------------------------------------------------------------------------
__global__ __launch_bounds__(256) void gemm_bt(const u16* __restrict__ A, const u16* __restrict__ Bm,
                                               float* __restrict__ C, const float* __restrict__ bias,
                                               int M, int N, int K) {
    __shared__ __align__(16) u16 sA[2][64 * 32];
    __shared__ __align__(16) u16 sB[2][64 * 32];
    const int t = threadIdx.x;
    const int wave = t >> 6, lane = t & 63;
    const int quad = lane >> 4, l16 = lane & 15;
    const int bm = blockIdx.y * 64, bn = blockIdx.x * 64;
    const int wr = wave >> 1, wc = wave & 1;

    f32x4 acc[2][2];
#pragma unroll
    for (int i = 0; i < 2; i++)
#pragma unroll
        for (int j = 0; j < 2; j++) acc[i][j] = f4zero();

    auto stage = [&](int k0, int bi) {
        gld_lds16((char*)&sA[bi][0] + wave * 1024,
                  A + (size_t)(bm + wave * 16 + (lane >> 2)) * K + k0 + (lane & 3) * 8);
        gld_lds16((char*)&sB[bi][0] + wave * 1024,
                  Bm + (size_t)(bn + wave * 16 + (lane >> 2)) * K + k0 + (lane & 3) * 8);
    };

    stage(0, 0);
    int cur = 0;
    for (int k0 = 0; k0 < K; k0 += 32) {
        __syncthreads();  // drains DMA of buf[cur]; protects buf[cur^1] reuse
        if (k0 + 32 < K) stage(k0 + 32, cur ^ 1);
        const u16* pA = &sA[cur][0];
        const u16* pB = &sB[cur][0];
        bf16x8 af[2], bfr[2];
#pragma unroll
        for (int mb = 0; mb < 2; mb++)
            af[mb] = *(const bf16x8*)(pA + (wr * 32 + mb * 16 + l16) * 32 + quad * 8);
#pragma unroll
        for (int nb = 0; nb < 2; nb++)
            bfr[nb] = *(const bf16x8*)(pB + (wc * 32 + nb * 16 + l16) * 32 + quad * 8);
#pragma unroll
        for (int mb = 0; mb < 2; mb++)
#pragma unroll
            for (int nb = 0; nb < 2; nb++)
                acc[mb][nb] = __builtin_amdgcn_mfma_f32_16x16x32_bf16(af[mb], bfr[nb], acc[mb][nb], 0, 0, 0);
        cur ^= 1;
    }
#pragma unroll
    for (int mb = 0; mb < 2; mb++)
#pragma unroll
        for (int nb = 0; nb < 2; nb++) {
            int col = bn + wc * 32 + nb * 16 + l16;
            float bv = bias ? bias[col] : 0.f;
#pragma unroll
            for (int r = 0; r < 4; r++) {
                int row = bm + wr * 32 + mb * 16 + quad * 4 + r;
                C[(size_t)row * N + col] = acc[mb][nb][r] + bv;
            }
        }
}

// ---------------------------------------------------------------------------
// QKV-GEMM (fused RoPE + flash-layout epilogue), 128x64 tiles, 4 vertical
// waves, grid 1152 = 4.5 WG/CU. Pow2 fast path for n->(zd,yh,xw) (R7).
// ---------------------------------------------------------------------------
__global__ __launch_bounds__(256) void gemm_qkv_rope(const u16* __restrict__ A, const u16* __restrict__ Bm,
                                                     const float* __restrict__ voxel,
                                                     const float* __restrict__ theta,
                                                     const int* __restrict__ gh_p, const int* __restrict__ gw_p,
                                                     u16* __restrict__ q_s, u16* __restrict__ k_s,
                                                     u16* __restrict__ vT, int M) {
    __shared__ __align__(16) u16 sA[2][128 * 32];
    __shared__ __align__(16) u16 sB[2][64 * 32];
    const int t = threadIdx.x;
    const int wave = t >> 6, lane = t & 63;
    const int quad = lane >> 4, l16 = lane & 15;
    const int bm = blockIdx.y * 128, bn = blockIdx.x * 64;
    const int K = DIM;

    f32x4 acc[2][4];
#pragma unroll
    for (int i = 0; i < 2; i++)
#pragma unroll
        for (int j = 0; j < 4; j++) acc[i][j] = f4zero();

    auto stage = [&](int k0, int bi) {
#pragma unroll
        for (int s = 0; s < 2; ++s) {
            int ci = wave * 2 + s;  // A chunk: rows ci*16..ci*16+15
            gld_lds16((char*)&sA[bi][0] + ci * 1024,
                      A + (size_t)(bm + ci * 16 + (lane >> 2)) * K + k0 + (lane & 3) * 8);
        }
        gld_lds16((char*)&sB[bi][0] + wave * 1024,
                  Bm + (size_t)(bn + wave * 16 + (lane >> 2)) * K + k0 + (lane & 3) * 8);
    };

    stage(0, 0);
    int cur = 0;
    for (int k0 = 0; k0 < K; k0 += 32) {
        __syncthreads();
        if (k0 + 32 < K) stage(k0 + 32, cur ^ 1);
        const u16* pA = &sA[cur][0];
        const u16* pB = &sB[cur][0];
        bf16x8 af[2], bfr[4];
#pragma unroll
        for (int mb = 0; mb < 2; mb++)
            af[mb] = *(const bf16x8*)(pA + (wave * 32 + mb * 16 + l16) * 32 + quad * 8);
#pragma unroll
        for (int nb = 0; nb < 4; nb++)
            bfr[nb] = *(const bf16x8*)(pB + (nb * 16 + l16) * 32 + quad * 8);
#pragma unroll
        for (int mb = 0; mb < 2; mb++)
#pragma unroll
            for (int nb = 0; nb < 4; nb++)
                acc[mb][nb] = __builtin_amdgcn_mfma_f32_16x16x32_bf16(af[mb], bfr[nb], acc[mb][nb], 0, 0, 0);
        cur ^= 1;
    }

    // ---------------- fused epilogue ----------------
    const int col0 = bn;                     // 64-col block = one head window
    const int typ = col0 / DIM;              // 0=Q, 1=K, 2=V (block-uniform)
    const int h = (col0 % DIM) >> 6;
    const int b = bm / NTOK;
    const int n0 = (bm % NTOK) + wave * 32;  // wave's token base (mult of 32)
    const size_t bh = (size_t)b * NHEADS + h;

    if (typ == 2) {
        // ---- V: register-local fragment-major pack (one chunk per wave) ----
        int chunk = ((bm % NTOK) >> 5) + wave;
        u16* base = vT + ((size_t)bh * 64 + chunk) * 2048;
#pragma unroll
        for (int nb = 0; nb < 4; nb++) {
            u32 w0 = (u32)f2bf(acc[0][nb][0]) | ((u32)f2bf(acc[0][nb][1]) << 16);
            u32 w1 = (u32)f2bf(acc[0][nb][2]) | ((u32)f2bf(acc[0][nb][3]) << 16);
            u32 w2 = (u32)f2bf(acc[1][nb][0]) | ((u32)f2bf(acc[1][nb][1]) << 16);
            u32 w3 = (u32)f2bf(acc[1][nb][2]) | ((u32)f2bf(acc[1][nb][3]) << 16);
            *(uint4*)(base + nb * 512 + lane * 8) = make_uint4(w0, w1, w2, w3);
        }
    } else {
        // ---- Q/K: in-register RoPE ----
        const int gh = *gh_p, gw = *gw_p;
        const bool p2 = ((gw & (gw - 1)) == 0) && ((gh & (gh - 1)) == 0);
        const int wsh = 31 - __builtin_clz(gw), hsh = 31 - __builtin_clz(gh);
        const float qsc = (typ == 0) ? 0.125f * LOG2E : 1.0f;
        const float th0 = theta[h * DHALF + l16];
        const float th1 = theta[h * DHALF + 16 + l16];
        const int ax0 = l16 % 3, ax1 = (16 + l16) % 3;
        const float vx0 = voxel[ax0], vx1 = voxel[ax1];
#pragma unroll
        for (int mb = 0; mb < 2; mb++)
#pragma unroll
            for (int r = 0; r < 4; r++) {
                int n = n0 + mb * 16 + quad * 4 + r;
                int xw, yh, zd;
                if (p2) {  // pow2 grid (the actual case: 8x16x16): 3 ops
                    xw = n & (gw - 1);
                    int rem = n >> wsh;
                    yh = rem & (gh - 1);
                    zd = rem >> hsh;
                } else {   // generic path, branched around at runtime
                    xw = n % gw;
                    int rem = n / gw;
                    yh = rem % gh;
                    zd = rem / gh;
                }
                float c0 = (float)(ax0 == 0 ? zd : (ax0 == 1 ? yh : xw)) * vx0;
                float c1 = (float)(ax1 == 0 ? zd : (ax1 == 1 ? yh : xw)) * vx1;
                float s0, co0, s1, co1;
                __sincosf(c0 * th0, &s0, &co0);
                __sincosf(c1 * th1, &s1, &co1);
                float t1a = acc[mb][0][r], t2a = acc[mb][2][r];
                float o1a = (t1a * co0 - t2a * s0) * qsc, o2a = (t1a * s0 + t2a * co0) * qsc;
                float t1b = acc[mb][1][r], t2b = acc[mb][3][r];
                float o1b = (t1b * co1 - t2b * s1) * qsc, o2b = (t1b * s1 + t2b * co1) * qsc;
                if (typ == 0) {
                    u16* dq = q_s + (bh * NTOK + n) * HDIM;
                    dq[l16] = f2bf(o1a);
                    dq[l16 + DHALF] = f2bf(o2a);
                    dq[16 + l16] = f2bf(o1b);
                    dq[48 + l16] = f2bf(o2b);
                } else {
                    // fragment-major K (matches flash's kf read pattern)
                    int gm = wave * 2 + mb;
                    int tile_i = ((bm % NTOK) >> 6) + (gm >> 2);
                    int g = gm & 3;
                    int k16 = quad * 4 + r;
                    size_t baseo = bh * (size_t)NTOK * HDIM + (size_t)tile_i * 4096 + g * 1024;
                    int j = l16 & 7;
                    size_t oa = baseo + (size_t)(((l16 >> 3) * 16 + k16) * 8 + j);
                    size_t ob = baseo + (size_t)((((2 + (l16 >> 3)) * 16) + k16) * 8 + j);
                    k_s[oa] = f2bf(o1a);
                    k_s[oa + 512] = f2bf(o2a);
                    k_s[ob] = f2bf(o1b);
                    k_s[ob + 512] = f2bf(o2b);
                }
            }
    }
}

// ---------------------------------------------------------------------------
// Flash attention v11 = R7 (50.1us) + explicit 2-deep c-pipeline (T15-style).
// R7 counters: MfmaUtil 23.5 / VALU 62 / nothing saturated -> intra-wave
// serial chain {S-MFMA -> 8 dep exp2 -> PV-MFMA} is the stall. The two
// c-iterations per kt-tile are independent until the o-accumulate, so:
// S(c0), S(c1) on the matrix pipe FIRST, then exp(c0) on TRANS overlaps
// nothing-left-to-wait-for, PV(c0) overlaps exp(c1). VGPR +~50 (kf both c
// + st[2][2]); must stay <=128 for 4 waves/SIMD (need 3).
// setprio kept (R7: +6.5% measured). Everything else unchanged.
// ---------------------------------------------------------------------------
__global__ __launch_bounds__(256) void flash_attn(const u16* __restrict__ Q, const u16* __restrict__ Kp,
                                                  const u16* __restrict__ Vp, u16* __restrict__ Out, int NBH) {
    int i = blockIdx.x;
    int bh_i = i % NBH;   // all of a bh's WGs land on XCD bh%8 (24%8==0)
    int qt = i / NBH;     // 0..31
    int b = bh_i / NHEADS, h = bh_i % NHEADS;
    int t = threadIdx.x, wave = t >> 6, lane = t & 63, quad = lane >> 4, l16 = lane & 15;
    size_t bh = (size_t)b * NHEADS + h;
    const u16* Qb = Q + bh * NTOK * HDIM;
    const u16* Kb = Kp + bh * NTOK * HDIM;  // frag-major 4096-elem tiles
    const u16* Vb = Vp + bh * NTOK * HDIM;  // frag-major: 2 chunks x 2048 per tile

    __shared__ __align__(16) u16 smem[2][8192];  // [buf][K 4096 | V 4096] = 32KB

    const int q0 = qt * 64 + wave * 16;  // 16 q-rows per wave
    bf16x8 qf[2];
#pragma unroll
    for (int kc = 0; kc < 2; kc++)
        qf[kc] = *(const bf16x8*)(Qb + (size_t)(q0 + l16) * HDIM + kc * 32 + quad * 8);

    // ones B-frag: col 0 accumulates the P row-sum
    s16x8 ov;
#pragma unroll
    for (int j = 0; j < 8; j++) ov[j] = (l16 == 0) ? (short)0x3F80 : (short)0;

    f32x4 o[5];
#pragma unroll
    for (int db = 0; db < 5; db++) o[db] = f4zero();

    // stage 8KB K + 8KB V of tile kt into buffer bi (4 x 1KB DMA per wave)
    auto stage = [&](int kt, int bi) {
        const u16* Kg = Kb + (size_t)kt * 4096;
        const u16* Vg = Vb + (size_t)kt * 4096;
        u16* buf = &smem[bi][0];
#pragma unroll
        for (int s = 0; s < 2; s++) {
            gld_lds16(buf + (wave * 2 + s) * 512, Kg + (wave * 2 + s) * 512 + lane * 8);
            gld_lds16(buf + 4096 + (wave * 2 + s) * 512, Vg + (wave * 2 + s) * 512 + lane * 8);
        }
    };

    stage(0, 0);
    int cur = 0;
    for (int kt = 0; kt < NTOK / 64; ++kt) {
        __syncthreads();  // drains DMA of buf[cur]; protects buf[cur^1] reuse
        if (kt + 1 < NTOK / 64) stage(kt + 1, cur ^ 1);
        const u16* sK = &smem[cur][0];
        const u16* sV = &smem[cur][4096];

        // ---- load K-fragments for BOTH c up front ----
        bf16x8 kf[2][2][2];  // [c][kb2][kc]
#pragma unroll
        for (int c = 0; c < 2; ++c)
#pragma unroll
            for (int kb2 = 0; kb2 < 2; kb2++)
#pragma unroll
                for (int kc = 0; kc < 2; kc++)
                    kf[c][kb2][kc] = *(const bf16x8*)(sK + ((c * 2 + kb2) * 2 + kc) * 512 + lane * 8);

        // ---- S-MFMAs for both c back-to-back (fills matrix pipe) ----
        f32x4 st[2][2];
        __builtin_amdgcn_s_setprio(1);
#pragma unroll
        for (int c = 0; c < 2; ++c) {
            f32x4 z = f4zero();
            z = __builtin_amdgcn_mfma_f32_16x16x32_bf16(kf[c][0][0], qf[0], z, 0, 0, 0);
            st[c][0] = __builtin_amdgcn_mfma_f32_16x16x32_bf16(kf[c][0][1], qf[1], z, 0, 0, 0);
            f32x4 z2 = f4zero();
            z2 = __builtin_amdgcn_mfma_f32_16x16x32_bf16(kf[c][1][0], qf[0], z2, 0, 0, 0);
            st[c][1] = __builtin_amdgcn_mfma_f32_16x16x32_bf16(kf[c][1][1], qf[1], z2, 0, 0, 0);
        }
        __builtin_amdgcn_s_setprio(0);

        // ---- per-c: exp2 (TRANS) then PV (matrix) -> exp(c1) overlaps PV(c0) ----
#pragma unroll
        for (int c = 0; c < 2; ++c) {
            s16x8 bv[4];
#pragma unroll
            for (int db = 0; db < 4; db++)
                bv[db] = *(const s16x8*)(sV + c * 2048 + db * 512 + lane * 8);
            bf16x8 pb;
#pragma unroll
            for (int r = 0; r < 4; r++) {
                pb[r] = (__bf16)__builtin_exp2f(st[c][0][r]);
                pb[r + 4] = (__bf16)__builtin_exp2f(st[c][1][r]);
            }
            __builtin_amdgcn_s_setprio(1);
#pragma unroll
            for (int db = 0; db < 4; db++)
                o[db] = __builtin_amdgcn_mfma_f32_16x16x32_bf16(pb, __builtin_bit_cast(bf16x8, bv[db]),
                                                                o[db], 0, 0, 0);
            o[4] = __builtin_amdgcn_mfma_f32_16x16x32_bf16(pb, __builtin_bit_cast(bf16x8, ov),
                                                           o[4], 0, 0, 0);
            __builtin_amdgcn_s_setprio(0);
        }
        cur ^= 1;
    }

    // epilogue: broadcast row-sum from col-0 lanes, normalize, store bf16
#pragma unroll
    for (int r = 0; r < 4; r++) {
        float s = __shfl(o[4][r], lane & 48);  // lane quad*16 holds the sum
        float inv = 1.0f / s;
        int n = q0 + quad * 4 + r;
        u16* dst = Out + ((size_t)b * NTOK + n) * DIM + h * HDIM + l16;
#pragma unroll
        for (int db = 0; db < 4; db++)
            dst[db * 16] = f2bf(o[db][r] * inv);
    }
}

// ---------------------------------------------------------------------------
extern "C" void kernel_launch(void* const* d_in, const int* in_sizes, int n_in,
                              void* d_out, int out_size, void* d_ws, size_t ws_size,
                              hipStream_t stream) {
    const float* x = (const float*)d_in[0];
    const float* voxel = (const float*)d_in[1];
    const float* w_qkv = (const float*)d_in[2];
    const float* w_proj = (const float*)d_in[3];
    const float* b_proj = (const float*)d_in[4];
    const float* theta = (const float*)d_in[5];
    const int* gh_p = (const int*)d_in[7];
    const int* gw_p = (const int*)d_in[8];
    const int B = in_sizes[0] / (NTOK * DIM);
    const int M = B * NTOK;

    char* p = (char*)d_ws;
    u16* xb = (u16*)p;       p += (size_t)M * DIM * 2;
    u16* wqkvb = (u16*)p;    p += (size_t)3 * DIM * DIM * 2;
    u16* wprojb = (u16*)p;   p += (size_t)DIM * DIM * 2;
    u16* q_s = (u16*)p;      p += (size_t)M * DIM * 2;
    u16* k_s = (u16*)p;      p += (size_t)M * DIM * 2;
    u16* vT = (u16*)p;       p += (size_t)M * DIM * 2;
    u16* attn = (u16*)p;     p += (size_t)M * DIM * 2;

    int na4 = M * DIM / 4, nb4 = 3 * DIM * DIM / 4, nc4 = DIM * DIM / 4;
    cast3_f32_to_bf16<<<dim3((na4 + nb4 + nc4 + 255) / 256), 256, 0, stream>>>(
        x, xb, na4, w_qkv, wqkvb, nb4, w_proj, wprojb, nc4);

    // QKV GEMM with fused RoPE + flash-layout epilogue: 128x64 tiles, 1152 WG
    gemm_qkv_rope<<<dim3(QKVN / 64, M / 128), 256, 0, stream>>>(
        xb, wqkvb, voxel, theta, gh_p, gw_p, q_s, k_s, vT, M);

    flash_attn<<<dim3((B * NHEADS * NTOK) / 64), 256, 0, stream>>>(q_s, k_s, vT, attn, B * NHEADS);

    // proj GEMM: 64x64 tiles -> 768 WG = 3 WG/CU
    gemm_bt<<<dim3(DIM / 64, M / 64), 256, 0, stream>>>(attn, wprojb, (float*)d_out, b_proj, M, DIM, DIM);
}

// Round 10
// 174.494 us; speedup vs baseline: 1.9479x; 1.0015x over previous
//
#include <hip/hip_runtime.h>
#include <stdint.h>

#define DIM 768
#define NHEADS 12
#define HDIM 64
#define DHALF 32
#define NTOK 2048
#define QKVN 2304
#define LOG2E 1.44269504088896340736f

typedef unsigned short u16;
typedef unsigned int u32;
typedef __bf16 bf16x8 __attribute__((ext_vector_type(8)));
typedef short s16x8 __attribute__((ext_vector_type(8)));
typedef float f32x4 __attribute__((ext_vector_type(4)));

__device__ __forceinline__ f32x4 f4zero() { f32x4 z = {0.f, 0.f, 0.f, 0.f}; return z; }

// fp32 -> bf16 bits, round-to-nearest-even
__device__ __forceinline__ u16 f2bf(float f) {
    u32 u = __builtin_bit_cast(u32, f);
    u32 r = (u + 0x7FFFu + ((u >> 16) & 1u)) >> 16;
    return (u16)r;
}

// async global->LDS, 16B per lane. LDS dest = wave-uniform base + lane*16.
__device__ __forceinline__ void gld_lds16(void* lds, const void* g) {
    __builtin_amdgcn_global_load_lds((const __attribute__((address_space(1))) u32*)g,
                                     (__attribute__((address_space(3))) u32*)lds,
                                     16, 0, 0);
}

// ---------------------------------------------------------------------------
// fused fp32 -> bf16 cast of x, w_qkv, w_proj (one launch)
// ---------------------------------------------------------------------------
__global__ __launch_bounds__(256) void cast3_f32_to_bf16(const float* __restrict__ a, u16* __restrict__ oa, int na4,
                                                         const float* __restrict__ b, u16* __restrict__ ob, int nb4,
                                                         const float* __restrict__ c, u16* __restrict__ oc, int nc4) {
    int i = blockIdx.x * 256 + threadIdx.x;
    const float* src;
    u16* dst;
    int j = i;
    if (i < na4) { src = a; dst = oa; }
    else if (i < na4 + nb4) { src = b; dst = ob; j = i - na4; }
    else if (i < na4 + nb4 + nc4) { src = c; dst = oc; j = i - na4 - nb4; }
    else return;
    float4 v = ((const float4*)src)[j];
    u32 w0 = (u32)f2bf(v.x) | ((u32)f2bf(v.y) << 16);
    u32 w1 = (u32)f2bf(v.z) | ((u32)f2bf(v.w) << 16);
    ((uint2*)dst)[j] = make_uint2(w0, w1);
}

// ---------------------------------------------------------------------------
// proj GEMM 64x64 tiles (768 WG = 3 WG/CU balanced), dbuf gld_lds.
// C[M,N] = A[M,K]*B[N,K]^T (+bias), bf16 in, fp32 out.
// ---------------------------------------------------------------------------
__global__ __launch_bounds__(256) void gemm_bt(const u16* __restrict__ A, const u16* __restrict__ Bm,
                                               float* __restrict__ C, const float* __restrict__ bias,
                                               int M, int N, int K) {
    __shared__ __align__(16) u16 sA[2][64 * 32];
    __shared__ __align__(16) u16 sB[2][64 * 32];
    const int t = threadIdx.x;
    const int wave = t >> 6, lane = t & 63;
    const int quad = lane >> 4, l16 = lane & 15;
    const int bm = blockIdx.y * 64, bn = blockIdx.x * 64;
    const int wr = wave >> 1, wc = wave & 1;

    f32x4 acc[2][2];
#pragma unroll
    for (int i = 0; i < 2; i++)
#pragma unroll
        for (int j = 0; j < 2; j++) acc[i][j] = f4zero();

    auto stage = [&](int k0, int bi) {
        gld_lds16((char*)&sA[bi][0] + wave * 1024,
                  A + (size_t)(bm + wave * 16 + (lane >> 2)) * K + k0 + (lane & 3) * 8);
        gld_lds16((char*)&sB[bi][0] + wave * 1024,
                  Bm + (size_t)(bn + wave * 16 + (lane >> 2)) * K + k0 + (lane & 3) * 8);
    };

    stage(0, 0);
    int cur = 0;
    for (int k0 = 0; k0 < K; k0 += 32) {
        __syncthreads();  // drains DMA of buf[cur]; protects buf[cur^1] reuse
        if (k0 + 32 < K) stage(k0 + 32, cur ^ 1);
        const u16* pA = &sA[cur][0];
        const u16* pB = &sB[cur][0];
        bf16x8 af[2], bfr[2];
#pragma unroll
        for (int mb = 0; mb < 2; mb++)
            af[mb] = *(const bf16x8*)(pA + (wr * 32 + mb * 16 + l16) * 32 + quad * 8);
#pragma unroll
        for (int nb = 0; nb < 2; nb++)
            bfr[nb] = *(const bf16x8*)(pB + (wc * 32 + nb * 16 + l16) * 32 + quad * 8);
#pragma unroll
        for (int mb = 0; mb < 2; mb++)
#pragma unroll
            for (int nb = 0; nb < 2; nb++)
                acc[mb][nb] = __builtin_amdgcn_mfma_f32_16x16x32_bf16(af[mb], bfr[nb], acc[mb][nb], 0, 0, 0);
        cur ^= 1;
    }
#pragma unroll
    for (int mb = 0; mb < 2; mb++)
#pragma unroll
        for (int nb = 0; nb < 2; nb++) {
            int col = bn + wc * 32 + nb * 16 + l16;
            float bv = bias ? bias[col] : 0.f;
#pragma unroll
            for (int r = 0; r < 4; r++) {
                int row = bm + wr * 32 + mb * 16 + quad * 4 + r;
                C[(size_t)row * N + col] = acc[mb][nb][r] + bv;
            }
        }
}

// ---------------------------------------------------------------------------
// QKV-GEMM (fused RoPE + flash-layout epilogue), 128x64 tiles, 4 vertical
// waves, grid 1152 = 4.5 WG/CU. Pow2 fast path for n->(zd,yh,xw).
// ---------------------------------------------------------------------------
__global__ __launch_bounds__(256) void gemm_qkv_rope(const u16* __restrict__ A, const u16* __restrict__ Bm,
                                                     const float* __restrict__ voxel,
                                                     const float* __restrict__ theta,
                                                     const int* __restrict__ gh_p, const int* __restrict__ gw_p,
                                                     u16* __restrict__ q_s, u16* __restrict__ k_s,
                                                     u16* __restrict__ vT, int M) {
    __shared__ __align__(16) u16 sA[2][128 * 32];
    __shared__ __align__(16) u16 sB[2][64 * 32];
    const int t = threadIdx.x;
    const int wave = t >> 6, lane = t & 63;
    const int quad = lane >> 4, l16 = lane & 15;
    const int bm = blockIdx.y * 128, bn = blockIdx.x * 64;
    const int K = DIM;

    f32x4 acc[2][4];
#pragma unroll
    for (int i = 0; i < 2; i++)
#pragma unroll
        for (int j = 0; j < 4; j++) acc[i][j] = f4zero();

    auto stage = [&](int k0, int bi) {
#pragma unroll
        for (int s = 0; s < 2; ++s) {
            int ci = wave * 2 + s;  // A chunk: rows ci*16..ci*16+15
            gld_lds16((char*)&sA[bi][0] + ci * 1024,
                      A + (size_t)(bm + ci * 16 + (lane >> 2)) * K + k0 + (lane & 3) * 8);
        }
        gld_lds16((char*)&sB[bi][0] + wave * 1024,
                  Bm + (size_t)(bn + wave * 16 + (lane >> 2)) * K + k0 + (lane & 3) * 8);
    };

    stage(0, 0);
    int cur = 0;
    for (int k0 = 0; k0 < K; k0 += 32) {
        __syncthreads();
        if (k0 + 32 < K) stage(k0 + 32, cur ^ 1);
        const u16* pA = &sA[cur][0];
        const u16* pB = &sB[cur][0];
        bf16x8 af[2], bfr[4];
#pragma unroll
        for (int mb = 0; mb < 2; mb++)
            af[mb] = *(const bf16x8*)(pA + (wave * 32 + mb * 16 + l16) * 32 + quad * 8);
#pragma unroll
        for (int nb = 0; nb < 4; nb++)
            bfr[nb] = *(const bf16x8*)(pB + (nb * 16 + l16) * 32 + quad * 8);
#pragma unroll
        for (int mb = 0; mb < 2; mb++)
#pragma unroll
            for (int nb = 0; nb < 4; nb++)
                acc[mb][nb] = __builtin_amdgcn_mfma_f32_16x16x32_bf16(af[mb], bfr[nb], acc[mb][nb], 0, 0, 0);
        cur ^= 1;
    }

    // ---------------- fused epilogue ----------------
    const int col0 = bn;                     // 64-col block = one head window
    const int typ = col0 / DIM;              // 0=Q, 1=K, 2=V (block-uniform)
    const int h = (col0 % DIM) >> 6;
    const int b = bm / NTOK;
    const int n0 = (bm % NTOK) + wave * 32;  // wave's token base (mult of 32)
    const size_t bh = (size_t)b * NHEADS + h;

    if (typ == 2) {
        // ---- V: register-local fragment-major pack (one chunk per wave) ----
        int chunk = ((bm % NTOK) >> 5) + wave;
        u16* base = vT + ((size_t)bh * 64 + chunk) * 2048;
#pragma unroll
        for (int nb = 0; nb < 4; nb++) {
            u32 w0 = (u32)f2bf(acc[0][nb][0]) | ((u32)f2bf(acc[0][nb][1]) << 16);
            u32 w1 = (u32)f2bf(acc[0][nb][2]) | ((u32)f2bf(acc[0][nb][3]) << 16);
            u32 w2 = (u32)f2bf(acc[1][nb][0]) | ((u32)f2bf(acc[1][nb][1]) << 16);
            u32 w3 = (u32)f2bf(acc[1][nb][2]) | ((u32)f2bf(acc[1][nb][3]) << 16);
            *(uint4*)(base + nb * 512 + lane * 8) = make_uint4(w0, w1, w2, w3);
        }
    } else {
        // ---- Q/K: in-register RoPE ----
        const int gh = *gh_p, gw = *gw_p;
        const bool p2 = ((gw & (gw - 1)) == 0) && ((gh & (gh - 1)) == 0);
        const int wsh = 31 - __builtin_clz(gw), hsh = 31 - __builtin_clz(gh);
        const float qsc = (typ == 0) ? 0.125f * LOG2E : 1.0f;
        const float th0 = theta[h * DHALF + l16];
        const float th1 = theta[h * DHALF + 16 + l16];
        const int ax0 = l16 % 3, ax1 = (16 + l16) % 3;
        const float vx0 = voxel[ax0], vx1 = voxel[ax1];
#pragma unroll
        for (int mb = 0; mb < 2; mb++)
#pragma unroll
            for (int r = 0; r < 4; r++) {
                int n = n0 + mb * 16 + quad * 4 + r;
                int xw, yh, zd;
                if (p2) {  // pow2 grid (the actual case: 8x16x16): 3 ops
                    xw = n & (gw - 1);
                    int rem = n >> wsh;
                    yh = rem & (gh - 1);
                    zd = rem >> hsh;
                } else {   // generic path, branched around at runtime
                    xw = n % gw;
                    int rem = n / gw;
                    yh = rem % gh;
                    zd = rem / gh;
                }
                float c0 = (float)(ax0 == 0 ? zd : (ax0 == 1 ? yh : xw)) * vx0;
                float c1 = (float)(ax1 == 0 ? zd : (ax1 == 1 ? yh : xw)) * vx1;
                float s0, co0, s1, co1;
                __sincosf(c0 * th0, &s0, &co0);
                __sincosf(c1 * th1, &s1, &co1);
                float t1a = acc[mb][0][r], t2a = acc[mb][2][r];
                float o1a = (t1a * co0 - t2a * s0) * qsc, o2a = (t1a * s0 + t2a * co0) * qsc;
                float t1b = acc[mb][1][r], t2b = acc[mb][3][r];
                float o1b = (t1b * co1 - t2b * s1) * qsc, o2b = (t1b * s1 + t2b * co1) * qsc;
                if (typ == 0) {
                    u16* dq = q_s + (bh * NTOK + n) * HDIM;
                    dq[l16] = f2bf(o1a);
                    dq[l16 + DHALF] = f2bf(o2a);
                    dq[16 + l16] = f2bf(o1b);
                    dq[48 + l16] = f2bf(o2b);
                } else {
                    // fragment-major K (matches flash's kf read pattern)
                    int gm = wave * 2 + mb;
                    int tile_i = ((bm % NTOK) >> 6) + (gm >> 2);
                    int g = gm & 3;
                    int k16 = quad * 4 + r;
                    size_t baseo = bh * (size_t)NTOK * HDIM + (size_t)tile_i * 4096 + g * 1024;
                    int j = l16 & 7;
                    size_t oa = baseo + (size_t)(((l16 >> 3) * 16 + k16) * 8 + j);
                    size_t ob = baseo + (size_t)((((2 + (l16 >> 3)) * 16) + k16) * 8 + j);
                    k_s[oa] = f2bf(o1a);
                    k_s[oa + 512] = f2bf(o2a);
                    k_s[ob] = f2bf(o1b);
                    k_s[ob + 512] = f2bf(o2b);
                }
            }
    }
}

// ---------------------------------------------------------------------------
// Flash attention — REVERT to the R7-measured best (50.1us): 4 waves x 16
// q-rows, grid 768 = 3 WG/CU, frag-major K/V (zero bank conflicts), dbuf
// gld_lds staging, fixed-base softmax, setprio around MFMA clusters (+6.5%
// measured R7). R8's 2-deep c-pipeline was null (51.0); R9's in-WG split-K
// raced under graph replay (mechanism not identified -> quarantined).
// ---------------------------------------------------------------------------
__global__ __launch_bounds__(256) void flash_attn(const u16* __restrict__ Q, const u16* __restrict__ Kp,
                                                  const u16* __restrict__ Vp, u16* __restrict__ Out, int NBH) {
    int i = blockIdx.x;
    int bh_i = i % NBH;   // all of a bh's WGs land on XCD bh%8 (24%8==0)
    int qt = i / NBH;     // 0..31
    int b = bh_i / NHEADS, h = bh_i % NHEADS;
    int t = threadIdx.x, wave = t >> 6, lane = t & 63, quad = lane >> 4, l16 = lane & 15;
    size_t bh = (size_t)b * NHEADS + h;
    const u16* Qb = Q + bh * NTOK * HDIM;
    const u16* Kb = Kp + bh * NTOK * HDIM;  // frag-major 4096-elem tiles
    const u16* Vb = Vp + bh * NTOK * HDIM;  // frag-major: 2 chunks x 2048 per tile

    __shared__ __align__(16) u16 smem[2][8192];  // [buf][K 4096 | V 4096] = 32KB

    const int q0 = qt * 64 + wave * 16;  // 16 q-rows per wave
    bf16x8 qf[2];
#pragma unroll
    for (int kc = 0; kc < 2; kc++)
        qf[kc] = *(const bf16x8*)(Qb + (size_t)(q0 + l16) * HDIM + kc * 32 + quad * 8);

    // ones B-frag: col 0 accumulates the P row-sum
    s16x8 ov;
#pragma unroll
    for (int j = 0; j < 8; j++) ov[j] = (l16 == 0) ? (short)0x3F80 : (short)0;

    f32x4 o[5];
#pragma unroll
    for (int db = 0; db < 5; db++) o[db] = f4zero();

    // stage 8KB K + 8KB V of tile kt into buffer bi (4 x 1KB DMA per wave)
    auto stage = [&](int kt, int bi) {
        const u16* Kg = Kb + (size_t)kt * 4096;
        const u16* Vg = Vb + (size_t)kt * 4096;
        u16* buf = &smem[bi][0];
#pragma unroll
        for (int s = 0; s < 2; s++) {
            gld_lds16(buf + (wave * 2 + s) * 512, Kg + (wave * 2 + s) * 512 + lane * 8);
            gld_lds16(buf + 4096 + (wave * 2 + s) * 512, Vg + (wave * 2 + s) * 512 + lane * 8);
        }
    };

    stage(0, 0);
    int cur = 0;
    for (int kt = 0; kt < NTOK / 64; ++kt) {
        __syncthreads();  // drains DMA of buf[cur]; protects buf[cur^1] reuse
        if (kt + 1 < NTOK / 64) stage(kt + 1, cur ^ 1);
        const u16* sK = &smem[cur][0];
        const u16* sV = &smem[cur][4096];
#pragma unroll
        for (int c = 0; c < 2; ++c) {
            bf16x8 kf[2][2];
#pragma unroll
            for (int kb2 = 0; kb2 < 2; kb2++)
#pragma unroll
                for (int kc = 0; kc < 2; kc++)
                    kf[kb2][kc] = *(const bf16x8*)(sK + ((c * 2 + kb2) * 2 + kc) * 512 + lane * 8);
            s16x8 bv[4];
#pragma unroll
            for (int db = 0; db < 4; db++)
                bv[db] = *(const s16x8*)(sV + c * 2048 + db * 512 + lane * 8);
            f32x4 st0, st1;
            __builtin_amdgcn_s_setprio(1);
            {
                f32x4 z = f4zero();
                z = __builtin_amdgcn_mfma_f32_16x16x32_bf16(kf[0][0], qf[0], z, 0, 0, 0);
                st0 = __builtin_amdgcn_mfma_f32_16x16x32_bf16(kf[0][1], qf[1], z, 0, 0, 0);
                f32x4 z2 = f4zero();
                z2 = __builtin_amdgcn_mfma_f32_16x16x32_bf16(kf[1][0], qf[0], z2, 0, 0, 0);
                st1 = __builtin_amdgcn_mfma_f32_16x16x32_bf16(kf[1][1], qf[1], z2, 0, 0, 0);
            }
            __builtin_amdgcn_s_setprio(0);
            bf16x8 pb;
#pragma unroll
            for (int r = 0; r < 4; r++) {
                pb[r] = (__bf16)__builtin_exp2f(st0[r]);
                pb[r + 4] = (__bf16)__builtin_exp2f(st1[r]);
            }
            __builtin_amdgcn_s_setprio(1);
#pragma unroll
            for (int db = 0; db < 4; db++)
                o[db] = __builtin_amdgcn_mfma_f32_16x16x32_bf16(pb, __builtin_bit_cast(bf16x8, bv[db]),
                                                                o[db], 0, 0, 0);
            o[4] = __builtin_amdgcn_mfma_f32_16x16x32_bf16(pb, __builtin_bit_cast(bf16x8, ov),
                                                           o[4], 0, 0, 0);
            __builtin_amdgcn_s_setprio(0);
        }
        cur ^= 1;
    }

    // epilogue: broadcast row-sum from col-0 lanes, normalize, store bf16
#pragma unroll
    for (int r = 0; r < 4; r++) {
        float s = __shfl(o[4][r], lane & 48);  // lane quad*16 holds the sum
        float inv = 1.0f / s;
        int n = q0 + quad * 4 + r;
        u16* dst = Out + ((size_t)b * NTOK + n) * DIM + h * HDIM + l16;
#pragma unroll
        for (int db = 0; db < 4; db++)
            dst[db * 16] = f2bf(o[db][r] * inv);
    }
}

// ---------------------------------------------------------------------------
extern "C" void kernel_launch(void* const* d_in, const int* in_sizes, int n_in,
                              void* d_out, int out_size, void* d_ws, size_t ws_size,
                              hipStream_t stream) {
    const float* x = (const float*)d_in[0];
    const float* voxel = (const float*)d_in[1];
    const float* w_qkv = (const float*)d_in[2];
    const float* w_proj = (const float*)d_in[3];
    const float* b_proj = (const float*)d_in[4];
    const float* theta = (const float*)d_in[5];
    const int* gh_p = (const int*)d_in[7];
    const int* gw_p = (const int*)d_in[8];
    const int B = in_sizes[0] / (NTOK * DIM);
    const int M = B * NTOK;

    char* p = (char*)d_ws;
    u16* xb = (u16*)p;       p += (size_t)M * DIM * 2;
    u16* wqkvb = (u16*)p;    p += (size_t)3 * DIM * DIM * 2;
    u16* wprojb = (u16*)p;   p += (size_t)DIM * DIM * 2;
    u16* q_s = (u16*)p;      p += (size_t)M * DIM * 2;
    u16* k_s = (u16*)p;      p += (size_t)M * DIM * 2;
    u16* vT = (u16*)p;       p += (size_t)M * DIM * 2;
    u16* attn = (u16*)p;     p += (size_t)M * DIM * 2;

    int na4 = M * DIM / 4, nb4 = 3 * DIM * DIM / 4, nc4 = DIM * DIM / 4;
    cast3_f32_to_bf16<<<dim3((na4 + nb4 + nc4 + 255) / 256), 256, 0, stream>>>(
        x, xb, na4, w_qkv, wqkvb, nb4, w_proj, wprojb, nc4);

    // QKV GEMM with fused RoPE + flash-layout epilogue: 128x64 tiles, 1152 WG
    gemm_qkv_rope<<<dim3(QKVN / 64, M / 128), 256, 0, stream>>>(
        xb, wqkvb, voxel, theta, gh_p, gw_p, q_s, k_s, vT, M);

    flash_attn<<<dim3((B * NHEADS * NTOK) / 64), 256, 0, stream>>>(q_s, k_s, vT, attn, B * NHEADS);

    // proj GEMM: 64x64 tiles -> 768 WG = 3 WG/CU
    gemm_bt<<<dim3(DIM / 64, M / 64), 256, 0, stream>>>(attn, wprojb, (float*)d_out, b_proj, M, DIM, DIM);
}